// Round 1
// baseline (1018.806 us; speedup 1.0000x reference)
//
#include <hip/hip_runtime.h>
#include <hip/hip_bf16.h>

#define NN 768
#define NSQ (768*768)
#define CS 384
#define CZ 128
#define HH 12
#define INF_ 1e5f
#define EPS_ 1e-8f
#define LN_EPS_ 1e-5f

typedef __attribute__((ext_vector_type(8))) short short8;
typedef __attribute__((ext_vector_type(4))) short short4_t;
typedef __attribute__((ext_vector_type(4))) float floatx4;

// ---- workspace layout (float element offsets) ----
constexpr size_t OFF_SLN  = 0;                           // 768*384
constexpr size_t OFF_PROJ = OFF_SLN + (size_t)768*384;   // 768*1152 : [q|k|v|qp|kp|vp]
constexpr size_t OFF_QPG  = OFF_PROJ + (size_t)768*1152; // 768*144
constexpr size_t OFF_KPG  = OFF_QPG + (size_t)768*144;   // 768*144
constexpr size_t OFF_VPG  = OFF_KPG + (size_t)768*144;   // 768*288
constexpr size_t OFF_WTBF = OFF_VPG + (size_t)768*288;   // 48*128 bf16
constexpr size_t OFF_HW   = OFF_WTBF + 4096;             // 16
constexpr size_t OFF_BIAS = OFF_HW + 16;                 // NSQ*12 bf16  (= NSQ*6 floats)
constexpr size_t OFF_ATT  = OFF_BIAS + (size_t)NSQ*6;    // 12*NSQ floats (softmaxed probs)
constexpr size_t OFF_PZ   = OFF_ATT + (size_t)12*NSQ;    // NSQ*32 bf16  (= NSQ*16 floats)
constexpr size_t OFF_OCAT = OFF_PZ + (size_t)NSQ*16;     // 768*960

__device__ __forceinline__ unsigned short f2bf(float f){
    unsigned int u = __float_as_uint(f);
    u = (u + 0x7fffu + ((u >> 16) & 1u)) >> 16;
    return (unsigned short)u;
}
__device__ __forceinline__ float bf2f(unsigned short u){
    return __uint_as_float((unsigned int)u << 16);
}

// ---- K0: zero ocat + zero out + bf16 W^T + softplus(head_weights)
__global__ __launch_bounds__(256) void k_setup(const float* __restrict__ Wb, const float* __restrict__ Wdz,
                                               const float* __restrict__ hwin, float* __restrict__ ws,
                                               float* __restrict__ out){
    int b = blockIdx.x, t = threadIdx.x;
    if (b < 2880){ ws[OFF_OCAT + (size_t)b*256 + t] = 0.f; return; }
    b -= 2880;
    if (b < 1152){ out[(size_t)b*256 + t] = 0.f; return; }
    b -= 1152;
    if (b < 24){
        unsigned short* wt = (unsigned short*)(ws + OFF_WTBF);
        int o = b*2 + (t>>7), k = t & 127;
        float v = 0.f;
        if (o < HH) v = Wb[k*HH + o];
        else if (o < 44) v = Wdz[k*32 + (o - HH)];
        wt[o*128 + k] = f2bf(v);
        return;
    }
    b -= 24;
    if (b == 0 && t < HH){
        ws[OFF_HW + t] = log1pf(expf(hwin[t])) * sqrtf(1.0f/54.0f);
    }
}

// ---- K1: LayerNorm(s)
__global__ __launch_bounds__(128) void k_lns(const float* __restrict__ s, const float* __restrict__ g,
                                             const float* __restrict__ b, float* __restrict__ ws){
    int i = blockIdx.x, t = threadIdx.x;
    const float* row = s + (size_t)i*CS;
    float x0 = row[t], x1 = row[t+128], x2 = row[t+256];
    float sum = x0+x1+x2, sq = x0*x0+x1*x1+x2*x2;
    for (int off = 32; off; off >>= 1){ sum += __shfl_down(sum, off, 64); sq += __shfl_down(sq, off, 64); }
    __shared__ float ls[2][2];
    int w = t >> 6;
    if ((t & 63) == 0){ ls[w][0] = sum; ls[w][1] = sq; }
    __syncthreads();
    sum = ls[0][0] + ls[1][0]; sq = ls[0][1] + ls[1][1];
    float mu = sum * (1.0f/CS);
    float var = sq * (1.0f/CS) - mu*mu;
    float rstd = rsqrtf(var + LN_EPS_);
    float* outp = ws + OFF_SLN + (size_t)i*CS;
    outp[t]     = (x0-mu)*rstd*g[t]     + b[t];
    outp[t+128] = (x1-mu)*rstd*g[t+128] + b[t+128];
    outp[t+256] = (x2-mu)*rstd*g[t+256] + b[t+256];
}

// ---- K2: projections, s_ln (768x384) @ W (384x1152)
__global__ __launch_bounds__(256) void k_proj(const float* __restrict__ Wq, const float* __restrict__ Wk,
                                              const float* __restrict__ Wv, const float* __restrict__ Wqp,
                                              const float* __restrict__ Wkp, const float* __restrict__ Wvp,
                                              float* __restrict__ ws){
    __shared__ float slds[16][CS];
    const float* sln = ws + OFF_SLN;
    int rt = blockIdx.x, ct = blockIdx.y, t = threadIdx.x;
    for (int ix = t; ix < 16*CS; ix += 256){
        int r = ix / CS, c = ix % CS;
        slds[r][c] = sln[(size_t)(rt*16 + r)*CS + c];
    }
    __syncthreads();
    int col = ct*128 + (t & 127);
    int rg = t >> 7;
    const float* wp; int stride;
    if      (col < 192){ wp = Wq  + col;       stride = 192; }
    else if (col < 384){ wp = Wk  + (col-192); stride = 192; }
    else if (col < 576){ wp = Wv  + (col-384); stride = 192; }
    else if (col < 720){ wp = Wqp + (col-576); stride = 144; }
    else if (col < 864){ wp = Wkp + (col-720); stride = 144; }
    else               { wp = Wvp + (col-864); stride = 288; }
    float acc[8] = {0,0,0,0,0,0,0,0};
    for (int k = 0; k < CS; k += 4){
        float w0 = wp[(size_t)k*stride];
        float w1 = wp[(size_t)(k+1)*stride];
        float w2 = wp[(size_t)(k+2)*stride];
        float w3 = wp[(size_t)(k+3)*stride];
        #pragma unroll
        for (int r = 0; r < 8; r++){
            floatx4 sv = *(const floatx4*)&slds[rg*8+r][k];
            acc[r] += sv[0]*w0 + sv[1]*w1 + sv[2]*w2 + sv[3]*w3;
        }
    }
    float* proj = ws + OFF_PROJ;
    for (int r = 0; r < 8; r++) proj[(size_t)(rt*16 + rg*8 + r)*1152 + col] = acc[r];
}

// ---- K2b: points to global frame
__global__ __launch_bounds__(192) void k_pts(const float* __restrict__ rot, const float* __restrict__ trans,
                                             float* __restrict__ ws){
    int i = blockIdx.x, p = threadIdx.x;
    const float* proj = ws + OFF_PROJ + (size_t)i*1152;
    const float* src; float* dst;
    if (p < 48)      { src = proj + 576 + p*3;       dst = ws + OFF_QPG + (size_t)i*144 + p*3; }
    else if (p < 96) { src = proj + 720 + (p-48)*3;  dst = ws + OFF_KPG + (size_t)i*144 + (p-48)*3; }
    else             { src = proj + 864 + (p-96)*3;  dst = ws + OFF_VPG + (size_t)i*288 + (p-96)*3; }
    float x = src[0], y = src[1], z = src[2];
    const float* R = rot + (size_t)i*9;
    const float* T = trans + (size_t)i*3;
    dst[0] = R[0]*x + R[1]*y + R[2]*z + T[0];
    dst[1] = R[3]*x + R[4]*y + R[5]*z + T[1];
    dst[2] = R[6]*x + R[7]*y + R[8]*z + T[2];
}

// ---- K3: LN(z) + [Wb|Wdz] via bf16 MFMA; bias & pz now stored as bf16
__global__ __launch_bounds__(256) void k_z(const float* __restrict__ z, const float* __restrict__ gz,
                                           const float* __restrict__ bz, float* __restrict__ ws){
    __shared__ unsigned short zlds[64][136];
    int t = threadIdx.x;
    int pb = blockIdx.x * 64;
    int lane32 = t & 31;
    int col = lane32 * 4;
    floatx4 g4 = *(const floatx4*)(gz + col);
    floatx4 b4 = *(const floatx4*)(bz + col);
    const float* zbase = z + (size_t)pb * 128;
    #pragma unroll
    for (int g = 0; g < 8; g++){
        int row = g*8 + (t >> 5);
        floatx4 v = *(const floatx4*)(zbase + (size_t)g*1024 + (size_t)t*4);
        float sum = v[0]+v[1]+v[2]+v[3];
        float sq  = v[0]*v[0]+v[1]*v[1]+v[2]*v[2]+v[3]*v[3];
        #pragma unroll
        for (int off = 1; off <= 16; off <<= 1){
            sum += __shfl_xor(sum, off, 64);
            sq  += __shfl_xor(sq , off, 64);
        }
        float mu = sum * (1.0f/128.0f);
        float rstd = rsqrtf(sq*(1.0f/128.0f) - mu*mu + LN_EPS_);
        short4_t sv;
        sv[0] = (short)f2bf((v[0]-mu)*rstd*g4[0] + b4[0]);
        sv[1] = (short)f2bf((v[1]-mu)*rstd*g4[1] + b4[1]);
        sv[2] = (short)f2bf((v[2]-mu)*rstd*g4[2] + b4[2]);
        sv[3] = (short)f2bf((v[3]-mu)*rstd*g4[3] + b4[3]);
        *(short4_t*)&zlds[row][col] = sv;
    }
    __syncthreads();
    const unsigned short* wt = (const unsigned short*)(ws + OFF_WTBF);
    int lane = t & 63, wv = t >> 6;
    int m = lane & 15, quad = lane >> 4;
    short8 bfrag[3][4];
    #pragma unroll
    for (int ot = 0; ot < 3; ot++)
        #pragma unroll
        for (int ks = 0; ks < 4; ks++){
            int o = ot*16 + m;
            bfrag[ot][ks] = *(const short8*)(wt + o*128 + ks*32 + quad*8);
        }
    floatx4 acc[3] = {{0.f,0.f,0.f,0.f},{0.f,0.f,0.f,0.f},{0.f,0.f,0.f,0.f}};
    int rbase = wv*16;
    #pragma unroll
    for (int ks = 0; ks < 4; ks++){
        short8 a = *(const short8*)&zlds[rbase + m][ks*32 + quad*8];
        acc[0] = __builtin_amdgcn_mfma_f32_16x16x32_bf16(a, bfrag[0][ks], acc[0], 0, 0, 0);
        acc[1] = __builtin_amdgcn_mfma_f32_16x16x32_bf16(a, bfrag[1][ks], acc[1], 0, 0, 0);
        acc[2] = __builtin_amdgcn_mfma_f32_16x16x32_bf16(a, bfrag[2][ks], acc[2], 0, 0, 0);
    }
    unsigned short* bias16 = (unsigned short*)(ws + OFF_BIAS);
    unsigned short* pz16   = (unsigned short*)(ws + OFF_PZ);
    #pragma unroll
    for (int ot = 0; ot < 3; ot++){
        int o = ot*16 + m;
        #pragma unroll
        for (int rg = 0; rg < 4; rg++){
            int pair = pb + rbase + quad*4 + rg;
            float val = acc[ot][rg];
            if (o < HH)      bias16[(size_t)o*NSQ + pair] = f2bf(val);
            else if (o < 44) pz16[(size_t)pair*32 + (o - HH)] = f2bf(val);
        }
    }
}

// ---- K4: fused logits + softmax. grid (96 i-tiles, 12 heads).
// threads: grp = t>>5 (i-row 0..7), jl = t&31 (j within tile). 24 j-tiles of 32.
// Per-thread keeps its 24 logits in registers (fully unrolled), double-buffered
// K-tile in LDS; att written once, post-softmax.
__global__ __launch_bounds__(256) void k_att(const float* __restrict__ smask, const int* __restrict__ idx,
                                             float* __restrict__ ws){
    __shared__ float qld[8][28];      // stride 28 floats: float4-aligned at c%4==0
    __shared__ float kld[2][32][30];  // stride 30: float2-aligned, 2-way bank alias (free)
    int it = blockIdx.x, h = blockIdx.y, t = threadIdx.x;
    const float* proj = ws + OFF_PROJ;
    const float* qpg  = ws + OFF_QPG;
    const float* kpg  = ws + OFF_KPG;
    float* att = ws + OFF_ATT + (size_t)h*NSQ;
    const unsigned short* bias16 = (const unsigned short*)(ws + OFF_BIAS) + (size_t)h*NSQ;

    // stage q for this head's 8 rows: [q(16) | qp(12)]
    for (int ix = t; ix < 8*28; ix += 256){
        int r = ix / 28, cc = ix % 28;
        int i = it*8 + r;
        qld[r][cc] = (cc < 16) ? proj[(size_t)i*1152 + h*16 + cc]
                               : qpg[(size_t)i*144 + h*12 + (cc-16)];
    }
    // stage k-tile 0
    for (int ix = t; ix < 32*28; ix += 256){
        int jj = ix / 28, cc = ix % 28;
        kld[0][jj][cc] = (cc < 16) ? proj[(size_t)jj*1152 + 192 + h*16 + cc]
                                   : kpg[(size_t)jj*144 + h*12 + (cc-16)];
    }
    __syncthreads();

    int grp = t >> 5, jl = t & 31;
    int i = it*8 + grp;
    int ires = idx[i];
    float si = smask[ires];
    float hwv = ws[OFF_HW + h];
    const unsigned short* brow = bias16 + (size_t)ires*NN;
    // hoist q fragment to registers (constant over jt)
    floatx4 q0 = *(const floatx4*)&qld[grp][0];
    floatx4 q1 = *(const floatx4*)&qld[grp][4];
    floatx4 q2 = *(const floatx4*)&qld[grp][8];
    floatx4 q3 = *(const floatx4*)&qld[grp][12];
    floatx4 qp0 = *(const floatx4*)&qld[grp][16];
    floatx4 qp1 = *(const floatx4*)&qld[grp][20];
    floatx4 qp2 = *(const floatx4*)&qld[grp][24];

    const float S1 = 0.14433756729740643f;
    const float S2 = 0.57735026918962576f;
    float lg[24];

    #pragma unroll
    for (int jt = 0; jt < 24; jt++){
        int b = jt & 1;
        if (jt < 23){
            int jn = (jt+1)*32;
            for (int ix = t; ix < 32*28; ix += 256){
                int jj = ix / 28, cc = ix % 28;
                int j = jn + jj;
                kld[1-b][jj][cc] = (cc < 16) ? proj[(size_t)j*1152 + 192 + h*16 + cc]
                                             : kpg[(size_t)j*144 + h*12 + (cc-16)];
            }
        }
        int j = jt*32 + jl;
        int jres = idx[j];
        float mterm = INF_ * (si*smask[jres] - 1.0f);
        const float* kr = &kld[b][jl][0];
        float2 k0 = *(const float2*)(kr+0),  k1 = *(const float2*)(kr+2);
        float2 k2 = *(const float2*)(kr+4),  k3 = *(const float2*)(kr+6);
        float2 k4 = *(const float2*)(kr+8),  k5 = *(const float2*)(kr+10);
        float2 k6 = *(const float2*)(kr+12), k7 = *(const float2*)(kr+14);
        float qk = q0[0]*k0.x+q0[1]*k0.y+q0[2]*k1.x+q0[3]*k1.y
                 + q1[0]*k2.x+q1[1]*k2.y+q1[2]*k3.x+q1[3]*k3.y
                 + q2[0]*k4.x+q2[1]*k4.y+q2[2]*k5.x+q2[3]*k5.y
                 + q3[0]*k6.x+q3[1]*k6.y+q3[2]*k7.x+q3[3]*k7.y;
        float2 p0 = *(const float2*)(kr+16), p1 = *(const float2*)(kr+18);
        float2 p2 = *(const float2*)(kr+20), p3 = *(const float2*)(kr+22);
        float2 p4 = *(const float2*)(kr+24), p5 = *(const float2*)(kr+26);
        float d0 = qp0[0]-p0.x, d1 = qp0[1]-p0.y, d2a = qp0[2]-p1.x, d3 = qp0[3]-p1.y;
        float d4 = qp1[0]-p2.x, d5 = qp1[1]-p2.y, d6 = qp1[2]-p3.x, d7 = qp1[3]-p3.y;
        float d8 = qp2[0]-p4.x, d9 = qp2[1]-p4.y, dA = qp2[2]-p5.x, dB = qp2[3]-p5.y;
        float d2 = d0*d0+d1*d1+d2a*d2a+d3*d3 + d4*d4+d5*d5+d6*d6+d7*d7 + d8*d8+d9*d9+dA*dA+dB*dB;
        float bv = bf2f(brow[jres]);
        lg[jt] = qk*S1 + S2*(bv + mterm) - 0.5f*hwv*d2;
        __syncthreads();
    }

    // softmax over the 768 keys: per-thread 24 values + 32-lane shuffle reduce
    float m = lg[0];
    #pragma unroll
    for (int jt = 1; jt < 24; jt++) m = fmaxf(m, lg[jt]);
    #pragma unroll
    for (int off = 16; off; off >>= 1) m = fmaxf(m, __shfl_xor(m, off, 64));
    float ssum = 0.f;
    #pragma unroll
    for (int jt = 0; jt < 24; jt++){ lg[jt] = expf(lg[jt] - m); ssum += lg[jt]; }
    #pragma unroll
    for (int off = 16; off; off >>= 1) ssum += __shfl_xor(ssum, off, 64);
    float inv = 1.0f / ssum;
    float* arow = att + (size_t)i*NN;
    #pragma unroll
    for (int jt = 0; jt < 24; jt++) arow[jt*32 + jl] = lg[jt] * inv;
}

// ---- K5: o and o_pt(global), j-split x3, atomic accumulate
__global__ __launch_bounds__(256) void k_ov(float* __restrict__ ws){
    __shared__ float wlds[128][41];
    __shared__ float plds[32][128];
    int h = blockIdx.x, it = blockIdx.y, zs = blockIdx.z, t = threadIdx.x;
    const float* proj = ws + OFF_PROJ;
    const float* vpg  = ws + OFF_VPG;
    const float* att  = ws + OFF_ATT + (size_t)h*NSQ;
    int c = t & 63, isub = t >> 6;
    float acc[8] = {0,0,0,0,0,0,0,0};
    for (int jt = zs*2; jt < zs*2+2; jt++){
        __syncthreads();
        for (int ix = t; ix < 128*40; ix += 256){
            int jj = ix / 40, cc = ix % 40;
            int j = jt*128 + jj;
            wlds[jj][cc] = (cc < 16) ? proj[(size_t)j*1152 + 384 + h*16 + cc]
                                     : vpg[(size_t)j*288 + h*24 + (cc - 16)];
        }
        for (int ix = t; ix < 32*128; ix += 256){
            int rr = ix >> 7, jj = ix & 127;
            plds[rr][jj] = att[(size_t)(it*32 + rr)*NN + jt*128 + jj];
        }
        __syncthreads();
        if (c < 40){
            for (int jj = 0; jj < 128; jj += 4){
                float w0 = wlds[jj][c], w1 = wlds[jj+1][c], w2 = wlds[jj+2][c], w3 = wlds[jj+3][c];
                #pragma unroll
                for (int rr = 0; rr < 8; rr++){
                    floatx4 pv = *(floatx4*)&plds[isub*8+rr][jj];
                    acc[rr] += pv[0]*w0 + pv[1]*w1 + pv[2]*w2 + pv[3]*w3;
                }
            }
        }
    }
    if (c < 40){
        float* ocat = ws + OFF_OCAT;
        int col = (c < 16) ? (h*16 + c) : (576 + h*24 + (c - 16));
        for (int rr = 0; rr < 8; rr++){
            int i = it*32 + isub*8 + rr;
            atomicAdd(&ocat[(size_t)i*960 + col], acc[rr]);
        }
    }
}

// ---- K6: o_pair: grid (i, jt). pz now bf16.
__global__ __launch_bounds__(384) void k_opair(const int* __restrict__ idx, float* __restrict__ ws){
    __shared__ float plds[12][132];
    __shared__ float pzlds[128][33];
    int i = blockIdx.x, jt = blockIdx.y, t = threadIdx.x;
    int ires = idx[i];
    const unsigned int* pzg = (const unsigned int*)((const unsigned short*)(ws + OFF_PZ) + (size_t)ires*NN*32);
    const float* att = ws + OFF_ATT;
    for (int ix = t; ix < 12*128; ix += 384){
        int hh = ix >> 7, jj = ix & 127;
        plds[hh][jj] = att[(size_t)hh*NSQ + (size_t)i*NN + jt*128 + jj];
    }
    for (int ix = t; ix < 128*16; ix += 384){
        int jj = ix >> 4, cp = ix & 15;
        int jres = idx[jt*128 + jj];
        unsigned int u2 = pzg[(size_t)jres*16 + cp];
        pzlds[jj][cp*2]   = __uint_as_float(u2 << 16);
        pzlds[jj][cp*2+1] = __uint_as_float(u2 & 0xffff0000u);
    }
    __syncthreads();
    int h = t >> 5, c = t & 31;
    float acc = 0.f;
    #pragma unroll 4
    for (int j = 0; j < 128; j++)
        acc += plds[h][j] * pzlds[j][c];
    float* oc = ws + OFF_OCAT + (size_t)i*960 + 192;
    atomicAdd(&oc[h*32 + c], acc);
}

// ---- K6b: o_pt local frame + norms
__global__ __launch_bounds__(96) void k_ptfin(const float* __restrict__ rot, const float* __restrict__ trans,
                                              float* __restrict__ ws){
    int i = blockIdx.x, p = threadIdx.x;
    float* base = ws + OFF_OCAT + (size_t)i*960;
    float* pt = base + 576 + p*3;
    float x = pt[0] - trans[i*3+0];
    float y = pt[1] - trans[i*3+1];
    float z = pt[2] - trans[i*3+2];
    const float* R = rot + (size_t)i*9;
    float lx = R[0]*x + R[3]*y + R[6]*z;
    float ly = R[1]*x + R[4]*y + R[7]*z;
    float lz = R[2]*x + R[5]*y + R[8]*z;
    pt[0] = lx; pt[1] = ly; pt[2] = lz;
    base[864 + p] = sqrtf(lx*lx + ly*ly + lz*lz + EPS_);
}

// ---- K7: final GEMM, k-split x4, 8x2 register tile, atomic into zeroed out
__global__ __launch_bounds__(256) void k_out(const float* __restrict__ Wout, const float* __restrict__ Woutb,
                                             const float* __restrict__ Woutp, float* __restrict__ ws,
                                             float* __restrict__ out){
    __shared__ float olds[32][244];
    int it = blockIdx.x, ct = blockIdx.y, kc = blockIdx.z, t = threadIdx.x;
    const float* ocat = ws + OFF_OCAT;
    for (int ix = t; ix < 32*240; ix += 256){
        int r = ix / 240, kk = ix % 240;
        olds[r][kk] = ocat[(size_t)(it*32 + r)*960 + kc*240 + kk];
    }
    __syncthreads();
    int cl = t & 63, ig = t >> 6;
    int c0 = ct*128 + cl, c1 = c0 + 64;
    float acc0[8], acc1[8];
    #pragma unroll
    for (int r=0;r<8;r++){ acc0[r]=0; acc1[r]=0; }
    for (int kk = 0; kk < 240; kk += 4){
        float w0[4], w1[4];
        #pragma unroll
        for (int u = 0; u < 4; u++){
            int k = kc*240 + kk + u;
            const float* wrow = (k < 192) ? (Wout  + (size_t)k*CS)
                              : (k < 576) ? (Woutb + (size_t)(k-192)*CS)
                                          : (Woutp + (size_t)(k-576)*CS);
            w0[u] = wrow[c0]; w1[u] = wrow[c1];
        }
        #pragma unroll
        for (int r = 0; r < 8; r++){
            floatx4 ov = *(const floatx4*)&olds[ig*8 + r][kk];
            acc0[r] += ov[0]*w0[0] + ov[1]*w0[1] + ov[2]*w0[2] + ov[3]*w0[3];
            acc1[r] += ov[0]*w1[0] + ov[1]*w1[1] + ov[2]*w1[2] + ov[3]*w1[3];
        }
    }
    for (int r = 0; r < 8; r++){
        int i = it*32 + ig*8 + r;
        atomicAdd(&out[(size_t)i*CS + c0], acc0[r]);
        atomicAdd(&out[(size_t)i*CS + c1], acc1[r]);
    }
}

extern "C" void kernel_launch(void* const* d_in, const int* in_sizes, int n_in,
                              void* d_out, int out_size, void* d_ws, size_t ws_size,
                              hipStream_t stream){
    const float* s     = (const float*)d_in[0];
    const float* z     = (const float*)d_in[1];
    const float* rot   = (const float*)d_in[2];
    const float* trans = (const float*)d_in[3];
    const float* smask = (const float*)d_in[4];
    const float* gs    = (const float*)d_in[5];
    const float* bs    = (const float*)d_in[6];
    const float* gz    = (const float*)d_in[7];
    const float* bz    = (const float*)d_in[8];
    const float* Wq    = (const float*)d_in[9];
    const float* Wk    = (const float*)d_in[10];
    const float* Wv    = (const float*)d_in[11];
    const float* Wqp   = (const float*)d_in[12];
    const float* Wkp   = (const float*)d_in[13];
    const float* Wvp   = (const float*)d_in[14];
    const float* Wb    = (const float*)d_in[15];
    const float* Wdz   = (const float*)d_in[16];
    const float* hwin  = (const float*)d_in[17];
    const float* Wout  = (const float*)d_in[18];
    const float* Woutb = (const float*)d_in[19];
    const float* Woutp = (const float*)d_in[20];
    const int*   idx   = (const int*)d_in[21];
    float* ws  = (float*)d_ws;
    float* out = (float*)d_out;

    k_setup  <<<4057, 256, 0, stream>>>(Wb, Wdz, hwin, ws, out);
    k_lns    <<<768, 128, 0, stream>>>(s, gs, bs, ws);
    k_proj   <<<dim3(48, 9), 256, 0, stream>>>(Wq, Wk, Wv, Wqp, Wkp, Wvp, ws);
    k_pts    <<<768, 192, 0, stream>>>(rot, trans, ws);
    k_z      <<<9216, 256, 0, stream>>>(z, gz, bz, ws);
    k_att    <<<dim3(96, 12), 256, 0, stream>>>(smask, idx, ws);
    k_ov     <<<dim3(12, 24, 3), 256, 0, stream>>>(ws);
    k_opair  <<<dim3(768, 6), 384, 0, stream>>>(idx, ws);
    k_ptfin  <<<768, 96, 0, stream>>>(rot, trans, ws);
    k_out    <<<dim3(24, 3, 4), 256, 0, stream>>>(Wout, Woutb, Woutp, ws, out);
}

// Round 2
// 810.378 us; speedup vs baseline: 1.2572x; 1.2572x over previous
//
#include <hip/hip_runtime.h>
#include <hip/hip_bf16.h>

#define NN 768
#define NSQ (768*768)
#define CS 384
#define CZ 128
#define HH 12
#define INF_ 1e5f
#define EPS_ 1e-8f
#define LN_EPS_ 1e-5f

typedef __attribute__((ext_vector_type(8))) short short8;
typedef __attribute__((ext_vector_type(4))) short short4_t;
typedef __attribute__((ext_vector_type(4))) float floatx4;

// ---- workspace layout (float element offsets) ----
constexpr size_t OFF_SLN  = 0;                           // 768*384
constexpr size_t OFF_PROJ = OFF_SLN + (size_t)768*384;   // 768*1152 : [q|k|v|qp|kp|vp]
constexpr size_t OFF_QPG  = OFF_PROJ + (size_t)768*1152; // 768*144
constexpr size_t OFF_KPG  = OFF_QPG + (size_t)768*144;   // 768*144
constexpr size_t OFF_VPG  = OFF_KPG + (size_t)768*144;   // 768*288
constexpr size_t OFF_WTBF = OFF_VPG + (size_t)768*288;   // 48*128 bf16
constexpr size_t OFF_HW   = OFF_WTBF + 4096;             // 16
constexpr size_t OFF_BIAS = OFF_HW + 16;                 // NSQ*12 bf16  (= NSQ*6 floats)
constexpr size_t OFF_ATT  = OFF_BIAS + (size_t)NSQ*6;    // 12*NSQ floats (logits -> probs in place)
constexpr size_t OFF_PZ   = OFF_ATT + (size_t)12*NSQ;    // NSQ*32 bf16  (= NSQ*16 floats)
constexpr size_t OFF_OCAT = OFF_PZ + (size_t)NSQ*16;     // 768*960

__device__ __forceinline__ unsigned short f2bf(float f){
    unsigned int u = __float_as_uint(f);
    u = (u + 0x7fffu + ((u >> 16) & 1u)) >> 16;
    return (unsigned short)u;
}
__device__ __forceinline__ float bf2f(unsigned short u){
    return __uint_as_float((unsigned int)u << 16);
}

// ---- K0: zero ocat + zero out + bf16 W^T + softplus(head_weights)
__global__ __launch_bounds__(256) void k_setup(const float* __restrict__ Wb, const float* __restrict__ Wdz,
                                               const float* __restrict__ hwin, float* __restrict__ ws,
                                               float* __restrict__ out){
    int b = blockIdx.x, t = threadIdx.x;
    if (b < 2880){ ws[OFF_OCAT + (size_t)b*256 + t] = 0.f; return; }
    b -= 2880;
    if (b < 1152){ out[(size_t)b*256 + t] = 0.f; return; }
    b -= 1152;
    if (b < 24){
        unsigned short* wt = (unsigned short*)(ws + OFF_WTBF);
        int o = b*2 + (t>>7), k = t & 127;
        float v = 0.f;
        if (o < HH) v = Wb[k*HH + o];
        else if (o < 44) v = Wdz[k*32 + (o - HH)];
        wt[o*128 + k] = f2bf(v);
        return;
    }
    b -= 24;
    if (b == 0 && t < HH){
        ws[OFF_HW + t] = log1pf(expf(hwin[t])) * sqrtf(1.0f/54.0f);
    }
}

// ---- K1: LayerNorm(s)
__global__ __launch_bounds__(128) void k_lns(const float* __restrict__ s, const float* __restrict__ g,
                                             const float* __restrict__ b, float* __restrict__ ws){
    int i = blockIdx.x, t = threadIdx.x;
    const float* row = s + (size_t)i*CS;
    float x0 = row[t], x1 = row[t+128], x2 = row[t+256];
    float sum = x0+x1+x2, sq = x0*x0+x1*x1+x2*x2;
    for (int off = 32; off; off >>= 1){ sum += __shfl_down(sum, off, 64); sq += __shfl_down(sq, off, 64); }
    __shared__ float ls[2][2];
    int w = t >> 6;
    if ((t & 63) == 0){ ls[w][0] = sum; ls[w][1] = sq; }
    __syncthreads();
    sum = ls[0][0] + ls[1][0]; sq = ls[0][1] + ls[1][1];
    float mu = sum * (1.0f/CS);
    float var = sq * (1.0f/CS) - mu*mu;
    float rstd = rsqrtf(var + LN_EPS_);
    float* outp = ws + OFF_SLN + (size_t)i*CS;
    outp[t]     = (x0-mu)*rstd*g[t]     + b[t];
    outp[t+128] = (x1-mu)*rstd*g[t+128] + b[t+128];
    outp[t+256] = (x2-mu)*rstd*g[t+256] + b[t+256];
}

// ---- K2: projections, s_ln (768x384) @ W (384x1152)
__global__ __launch_bounds__(256) void k_proj(const float* __restrict__ Wq, const float* __restrict__ Wk,
                                              const float* __restrict__ Wv, const float* __restrict__ Wqp,
                                              const float* __restrict__ Wkp, const float* __restrict__ Wvp,
                                              float* __restrict__ ws){
    __shared__ float slds[16][CS];
    const float* sln = ws + OFF_SLN;
    int rt = blockIdx.x, ct = blockIdx.y, t = threadIdx.x;
    for (int ix = t; ix < 16*CS; ix += 256){
        int r = ix / CS, c = ix % CS;
        slds[r][c] = sln[(size_t)(rt*16 + r)*CS + c];
    }
    __syncthreads();
    int col = ct*128 + (t & 127);
    int rg = t >> 7;
    const float* wp; int stride;
    if      (col < 192){ wp = Wq  + col;       stride = 192; }
    else if (col < 384){ wp = Wk  + (col-192); stride = 192; }
    else if (col < 576){ wp = Wv  + (col-384); stride = 192; }
    else if (col < 720){ wp = Wqp + (col-576); stride = 144; }
    else if (col < 864){ wp = Wkp + (col-720); stride = 144; }
    else               { wp = Wvp + (col-864); stride = 288; }
    float acc[8] = {0,0,0,0,0,0,0,0};
    for (int k = 0; k < CS; k += 4){
        float w0 = wp[(size_t)k*stride];
        float w1 = wp[(size_t)(k+1)*stride];
        float w2 = wp[(size_t)(k+2)*stride];
        float w3 = wp[(size_t)(k+3)*stride];
        #pragma unroll
        for (int r = 0; r < 8; r++){
            floatx4 sv = *(const floatx4*)&slds[rg*8+r][k];
            acc[r] += sv[0]*w0 + sv[1]*w1 + sv[2]*w2 + sv[3]*w3;
        }
    }
    float* proj = ws + OFF_PROJ;
    for (int r = 0; r < 8; r++) proj[(size_t)(rt*16 + rg*8 + r)*1152 + col] = acc[r];
}

// ---- K2b: points to global frame
__global__ __launch_bounds__(192) void k_pts(const float* __restrict__ rot, const float* __restrict__ trans,
                                             float* __restrict__ ws){
    int i = blockIdx.x, p = threadIdx.x;
    const float* proj = ws + OFF_PROJ + (size_t)i*1152;
    const float* src; float* dst;
    if (p < 48)      { src = proj + 576 + p*3;       dst = ws + OFF_QPG + (size_t)i*144 + p*3; }
    else if (p < 96) { src = proj + 720 + (p-48)*3;  dst = ws + OFF_KPG + (size_t)i*144 + (p-48)*3; }
    else             { src = proj + 864 + (p-96)*3;  dst = ws + OFF_VPG + (size_t)i*288 + (p-96)*3; }
    float x = src[0], y = src[1], z = src[2];
    const float* R = rot + (size_t)i*9;
    const float* T = trans + (size_t)i*3;
    dst[0] = R[0]*x + R[1]*y + R[2]*z + T[0];
    dst[1] = R[3]*x + R[4]*y + R[5]*z + T[1];
    dst[2] = R[6]*x + R[7]*y + R[8]*z + T[2];
}

// ---- K3: LN(z) + [Wb|Wdz] via bf16 MFMA; bias & pz stored as bf16
__global__ __launch_bounds__(256) void k_z(const float* __restrict__ z, const float* __restrict__ gz,
                                           const float* __restrict__ bz, float* __restrict__ ws){
    __shared__ unsigned short zlds[64][136];
    int t = threadIdx.x;
    int pb = blockIdx.x * 64;
    int lane32 = t & 31;
    int col = lane32 * 4;
    floatx4 g4 = *(const floatx4*)(gz + col);
    floatx4 b4 = *(const floatx4*)(bz + col);
    const float* zbase = z + (size_t)pb * 128;
    #pragma unroll
    for (int g = 0; g < 8; g++){
        int row = g*8 + (t >> 5);
        floatx4 v = *(const floatx4*)(zbase + (size_t)g*1024 + (size_t)t*4);
        float sum = v[0]+v[1]+v[2]+v[3];
        float sq  = v[0]*v[0]+v[1]*v[1]+v[2]*v[2]+v[3]*v[3];
        #pragma unroll
        for (int off = 1; off <= 16; off <<= 1){
            sum += __shfl_xor(sum, off, 64);
            sq  += __shfl_xor(sq , off, 64);
        }
        float mu = sum * (1.0f/128.0f);
        float rstd = rsqrtf(sq*(1.0f/128.0f) - mu*mu + LN_EPS_);
        short4_t sv;
        sv[0] = (short)f2bf((v[0]-mu)*rstd*g4[0] + b4[0]);
        sv[1] = (short)f2bf((v[1]-mu)*rstd*g4[1] + b4[1]);
        sv[2] = (short)f2bf((v[2]-mu)*rstd*g4[2] + b4[2]);
        sv[3] = (short)f2bf((v[3]-mu)*rstd*g4[3] + b4[3]);
        *(short4_t*)&zlds[row][col] = sv;
    }
    __syncthreads();
    const unsigned short* wt = (const unsigned short*)(ws + OFF_WTBF);
    int lane = t & 63, wv = t >> 6;
    int m = lane & 15, quad = lane >> 4;
    short8 bfrag[3][4];
    #pragma unroll
    for (int ot = 0; ot < 3; ot++)
        #pragma unroll
        for (int ks = 0; ks < 4; ks++){
            int o = ot*16 + m;
            bfrag[ot][ks] = *(const short8*)(wt + o*128 + ks*32 + quad*8);
        }
    floatx4 acc[3] = {{0.f,0.f,0.f,0.f},{0.f,0.f,0.f,0.f},{0.f,0.f,0.f,0.f}};
    int rbase = wv*16;
    #pragma unroll
    for (int ks = 0; ks < 4; ks++){
        short8 a = *(const short8*)&zlds[rbase + m][ks*32 + quad*8];
        acc[0] = __builtin_amdgcn_mfma_f32_16x16x32_bf16(a, bfrag[0][ks], acc[0], 0, 0, 0);
        acc[1] = __builtin_amdgcn_mfma_f32_16x16x32_bf16(a, bfrag[1][ks], acc[1], 0, 0, 0);
        acc[2] = __builtin_amdgcn_mfma_f32_16x16x32_bf16(a, bfrag[2][ks], acc[2], 0, 0, 0);
    }
    unsigned short* bias16 = (unsigned short*)(ws + OFF_BIAS);
    unsigned short* pz16   = (unsigned short*)(ws + OFF_PZ);
    #pragma unroll
    for (int ot = 0; ot < 3; ot++){
        int o = ot*16 + m;
        #pragma unroll
        for (int rg = 0; rg < 4; rg++){
            int pair = pb + rbase + quad*4 + rg;
            float val = acc[ot][rg];
            if (o < HH)      bias16[(size_t)o*NSQ + pair] = f2bf(val);
            else if (o < 44) pz16[(size_t)pair*32 + (o - HH)] = f2bf(val);
        }
    }
}

// ---- K4: logits (round-0 structure, bias read from bf16 buffer)
__global__ __launch_bounds__(256) void k_logits(const float* __restrict__ smask, const int* __restrict__ idx,
                                                float* __restrict__ ws){
    __shared__ float qlds[8][336];
    __shared__ float klds[32][338];
    int it = blockIdx.x, jt = blockIdx.y, t = threadIdx.x;
    const float* proj = ws + OFF_PROJ;
    const float* qpg  = ws + OFF_QPG;
    const float* kpg  = ws + OFF_KPG;
    const float* hw   = ws + OFF_HW;
    const unsigned short* bias16 = (const unsigned short*)(ws + OFF_BIAS);
    float* att = ws + OFF_ATT;
    for (int ix = t; ix < 8*336; ix += 256){
        int r = ix / 336, c = ix % 336;
        int i = it*8 + r;
        qlds[r][c] = (c < 192) ? proj[(size_t)i*1152 + c] : qpg[(size_t)i*144 + (c - 192)];
    }
    for (int ix = t; ix < 32*336; ix += 256){
        int r = ix / 336, c = ix % 336;
        int j = jt*32 + r;
        klds[r][c] = (c < 192) ? proj[(size_t)j*1152 + 192 + c] : kpg[(size_t)j*144 + (c - 192)];
    }
    __syncthreads();
    int jl = t & 31, grp = t >> 5;
    int i = it*8 + grp, j = jt*32 + jl;
    int ires = idx[i], jres = idx[j];
    float mterm = INF_ * (smask[ires]*smask[jres] - 1.0f);
    const float S1 = 0.14433756729740643f;
    const float S2 = 0.57735026918962576f;
    for (int h = 0; h < HH; h++){
        floatx4 q0 = *(const floatx4*)&qlds[grp][h*16];
        floatx4 q1 = *(const floatx4*)&qlds[grp][h*16+4];
        floatx4 q2 = *(const floatx4*)&qlds[grp][h*16+8];
        floatx4 q3 = *(const floatx4*)&qlds[grp][h*16+12];
        const float* kr = &klds[jl][h*16];
        float2 k0 = *(const float2*)(kr+0),  k1 = *(const float2*)(kr+2);
        float2 k2 = *(const float2*)(kr+4),  k3 = *(const float2*)(kr+6);
        float2 k4 = *(const float2*)(kr+8),  k5 = *(const float2*)(kr+10);
        float2 k6 = *(const float2*)(kr+12), k7 = *(const float2*)(kr+14);
        float qk = q0[0]*k0.x+q0[1]*k0.y+q0[2]*k1.x+q0[3]*k1.y
                 + q1[0]*k2.x+q1[1]*k2.y+q1[2]*k3.x+q1[3]*k3.y
                 + q2[0]*k4.x+q2[1]*k4.y+q2[2]*k5.x+q2[3]*k5.y
                 + q3[0]*k6.x+q3[1]*k6.y+q3[2]*k7.x+q3[3]*k7.y;
        floatx4 qp0 = *(const floatx4*)&qlds[grp][192+h*12];
        floatx4 qp1 = *(const floatx4*)&qlds[grp][192+h*12+4];
        floatx4 qp2 = *(const floatx4*)&qlds[grp][192+h*12+8];
        const float* kp = &klds[jl][192+h*12];
        float2 p0 = *(const float2*)(kp+0), p1 = *(const float2*)(kp+2);
        float2 p2 = *(const float2*)(kp+4), p3 = *(const float2*)(kp+6);
        float2 p4 = *(const float2*)(kp+8), p5 = *(const float2*)(kp+10);
        float d0 = qp0[0]-p0.x, d1 = qp0[1]-p0.y, d2a = qp0[2]-p1.x, d3 = qp0[3]-p1.y;
        float d4 = qp1[0]-p2.x, d5 = qp1[1]-p2.y, d6 = qp1[2]-p3.x, d7 = qp1[3]-p3.y;
        float d8 = qp2[0]-p4.x, d9 = qp2[1]-p4.y, dA = qp2[2]-p5.x, dB = qp2[3]-p5.y;
        float d2 = d0*d0+d1*d1+d2a*d2a+d3*d3 + d4*d4+d5*d5+d6*d6+d7*d7 + d8*d8+d9*d9+dA*dA+dB*dB;
        float bv = bf2f(bias16[(size_t)h*NSQ + (size_t)ires*NN + jres]);
        float lg = qk*S1 + S2*(bv + mterm) - 0.5f*hw[h]*d2;
        att[(size_t)h*NSQ + (size_t)i*NN + j] = lg;
    }
}

// ---- K4c: softmax over j, float4
__global__ __launch_bounds__(192) void k_softmax(float* __restrict__ ws){
    int b = blockIdx.x, t = threadIdx.x;
    float* row = ws + OFF_ATT + (size_t)b*NN;
    floatx4 v = *(floatx4*)(row + t*4);
    float mx = fmaxf(fmaxf(v[0],v[1]), fmaxf(v[2],v[3]));
    for (int off = 32; off; off >>= 1) mx = fmaxf(mx, __shfl_xor(mx, off, 64));
    __shared__ float lsm[3];
    __shared__ float lss[3];
    int w = t >> 6;
    if ((t & 63) == 0) lsm[w] = mx;
    __syncthreads();
    mx = fmaxf(fmaxf(lsm[0], lsm[1]), lsm[2]);
    floatx4 e;
    e[0] = expf(v[0]-mx); e[1] = expf(v[1]-mx); e[2] = expf(v[2]-mx); e[3] = expf(v[3]-mx);
    float s = e[0]+e[1]+e[2]+e[3];
    for (int off = 32; off; off >>= 1) s += __shfl_xor(s, off, 64);
    if ((t & 63) == 0) lss[w] = s;
    __syncthreads();
    s = lss[0] + lss[1] + lss[2];
    float inv = 1.0f / s;
    e[0] *= inv; e[1] *= inv; e[2] *= inv; e[3] *= inv;
    *(floatx4*)(row + t*4) = e;
}

// ---- K5: o and o_pt(global), j-split x3, atomic accumulate
__global__ __launch_bounds__(256) void k_ov(float* __restrict__ ws){
    __shared__ float wlds[128][41];
    __shared__ float plds[32][128];
    int h = blockIdx.x, it = blockIdx.y, zs = blockIdx.z, t = threadIdx.x;
    const float* proj = ws + OFF_PROJ;
    const float* vpg  = ws + OFF_VPG;
    const float* att  = ws + OFF_ATT + (size_t)h*NSQ;
    int c = t & 63, isub = t >> 6;
    float acc[8] = {0,0,0,0,0,0,0,0};
    for (int jt = zs*2; jt < zs*2+2; jt++){
        __syncthreads();
        for (int ix = t; ix < 128*40; ix += 256){
            int jj = ix / 40, cc = ix % 40;
            int j = jt*128 + jj;
            wlds[jj][cc] = (cc < 16) ? proj[(size_t)j*1152 + 384 + h*16 + cc]
                                     : vpg[(size_t)j*288 + h*24 + (cc - 16)];
        }
        for (int ix = t; ix < 32*128; ix += 256){
            int rr = ix >> 7, jj = ix & 127;
            plds[rr][jj] = att[(size_t)(it*32 + rr)*NN + jt*128 + jj];
        }
        __syncthreads();
        if (c < 40){
            for (int jj = 0; jj < 128; jj += 4){
                float w0 = wlds[jj][c], w1 = wlds[jj+1][c], w2 = wlds[jj+2][c], w3 = wlds[jj+3][c];
                #pragma unroll
                for (int rr = 0; rr < 8; rr++){
                    floatx4 pv = *(floatx4*)&plds[isub*8+rr][jj];
                    acc[rr] += pv[0]*w0 + pv[1]*w1 + pv[2]*w2 + pv[3]*w3;
                }
            }
        }
    }
    if (c < 40){
        float* ocat = ws + OFF_OCAT;
        int col = (c < 16) ? (h*16 + c) : (576 + h*24 + (c - 16));
        for (int rr = 0; rr < 8; rr++){
            int i = it*32 + isub*8 + rr;
            atomicAdd(&ocat[(size_t)i*960 + col], acc[rr]);
        }
    }
}

// ---- K6: o_pair: grid (i, jt). pz bf16.
__global__ __launch_bounds__(384) void k_opair(const int* __restrict__ idx, float* __restrict__ ws){
    __shared__ float plds[12][132];
    __shared__ float pzlds[128][33];
    int i = blockIdx.x, jt = blockIdx.y, t = threadIdx.x;
    int ires = idx[i];
    const unsigned int* pzg = (const unsigned int*)((const unsigned short*)(ws + OFF_PZ) + (size_t)ires*NN*32);
    const float* att = ws + OFF_ATT;
    for (int ix = t; ix < 12*128; ix += 384){
        int hh = ix >> 7, jj = ix & 127;
        plds[hh][jj] = att[(size_t)hh*NSQ + (size_t)i*NN + jt*128 + jj];
    }
    for (int ix = t; ix < 128*16; ix += 384){
        int jj = ix >> 4, cp = ix & 15;
        int jres = idx[jt*128 + jj];
        unsigned int u2 = pzg[(size_t)jres*16 + cp];
        pzlds[jj][cp*2]   = __uint_as_float(u2 << 16);
        pzlds[jj][cp*2+1] = __uint_as_float(u2 & 0xffff0000u);
    }
    __syncthreads();
    int h = t >> 5, c = t & 31;
    float acc = 0.f;
    #pragma unroll 4
    for (int j = 0; j < 128; j++)
        acc += plds[h][j] * pzlds[j][c];
    float* oc = ws + OFF_OCAT + (size_t)i*960 + 192;
    atomicAdd(&oc[h*32 + c], acc);
}

// ---- K6b: o_pt local frame + norms
__global__ __launch_bounds__(96) void k_ptfin(const float* __restrict__ rot, const float* __restrict__ trans,
                                              float* __restrict__ ws){
    int i = blockIdx.x, p = threadIdx.x;
    float* base = ws + OFF_OCAT + (size_t)i*960;
    float* pt = base + 576 + p*3;
    float x = pt[0] - trans[i*3+0];
    float y = pt[1] - trans[i*3+1];
    float z = pt[2] - trans[i*3+2];
    const float* R = rot + (size_t)i*9;
    float lx = R[0]*x + R[3]*y + R[6]*z;
    float ly = R[1]*x + R[4]*y + R[7]*z;
    float lz = R[2]*x + R[5]*y + R[8]*z;
    pt[0] = lx; pt[1] = ly; pt[2] = lz;
    base[864 + p] = sqrtf(lx*lx + ly*ly + lz*lz + EPS_);
}

// ---- K7: final GEMM, k-split x4, 8x2 register tile, atomic into zeroed out
__global__ __launch_bounds__(256) void k_out(const float* __restrict__ Wout, const float* __restrict__ Woutb,
                                             const float* __restrict__ Woutp, float* __restrict__ ws,
                                             float* __restrict__ out){
    __shared__ float olds[32][244];
    int it = blockIdx.x, ct = blockIdx.y, kc = blockIdx.z, t = threadIdx.x;
    const float* ocat = ws + OFF_OCAT;
    for (int ix = t; ix < 32*240; ix += 256){
        int r = ix / 240, kk = ix % 240;
        olds[r][kk] = ocat[(size_t)(it*32 + r)*960 + kc*240 + kk];
    }
    __syncthreads();
    int cl = t & 63, ig = t >> 6;
    int c0 = ct*128 + cl, c1 = c0 + 64;
    float acc0[8], acc1[8];
    #pragma unroll
    for (int r=0;r<8;r++){ acc0[r]=0; acc1[r]=0; }
    for (int kk = 0; kk < 240; kk += 4){
        float w0[4], w1[4];
        #pragma unroll
        for (int u = 0; u < 4; u++){
            int k = kc*240 + kk + u;
            const float* wrow = (k < 192) ? (Wout  + (size_t)k*CS)
                              : (k < 576) ? (Woutb + (size_t)(k-192)*CS)
                                          : (Woutp + (size_t)(k-576)*CS);
            w0[u] = wrow[c0]; w1[u] = wrow[c1];
        }
        #pragma unroll
        for (int r = 0; r < 8; r++){
            floatx4 ov = *(const floatx4*)&olds[ig*8 + r][kk];
            acc0[r] += ov[0]*w0[0] + ov[1]*w0[1] + ov[2]*w0[2] + ov[3]*w0[3];
            acc1[r] += ov[0]*w1[0] + ov[1]*w1[1] + ov[2]*w1[2] + ov[3]*w1[3];
        }
    }
    for (int r = 0; r < 8; r++){
        int i = it*32 + ig*8 + r;
        atomicAdd(&out[(size_t)i*CS + c0], acc0[r]);
        atomicAdd(&out[(size_t)i*CS + c1], acc1[r]);
    }
}

extern "C" void kernel_launch(void* const* d_in, const int* in_sizes, int n_in,
                              void* d_out, int out_size, void* d_ws, size_t ws_size,
                              hipStream_t stream){
    const float* s     = (const float*)d_in[0];
    const float* z     = (const float*)d_in[1];
    const float* rot   = (const float*)d_in[2];
    const float* trans = (const float*)d_in[3];
    const float* smask = (const float*)d_in[4];
    const float* gs    = (const float*)d_in[5];
    const float* bs    = (const float*)d_in[6];
    const float* gz    = (const float*)d_in[7];
    const float* bz    = (const float*)d_in[8];
    const float* Wq    = (const float*)d_in[9];
    const float* Wk    = (const float*)d_in[10];
    const float* Wv    = (const float*)d_in[11];
    const float* Wqp   = (const float*)d_in[12];
    const float* Wkp   = (const float*)d_in[13];
    const float* Wvp   = (const float*)d_in[14];
    const float* Wb    = (const float*)d_in[15];
    const float* Wdz   = (const float*)d_in[16];
    const float* hwin  = (const float*)d_in[17];
    const float* Wout  = (const float*)d_in[18];
    const float* Woutb = (const float*)d_in[19];
    const float* Woutp = (const float*)d_in[20];
    const int*   idx   = (const int*)d_in[21];
    float* ws  = (float*)d_ws;
    float* out = (float*)d_out;

    k_setup  <<<4057, 256, 0, stream>>>(Wb, Wdz, hwin, ws, out);
    k_lns    <<<768, 128, 0, stream>>>(s, gs, bs, ws);
    k_proj   <<<dim3(48, 9), 256, 0, stream>>>(Wq, Wk, Wv, Wqp, Wkp, Wvp, ws);
    k_pts    <<<768, 192, 0, stream>>>(rot, trans, ws);
    k_z      <<<9216, 256, 0, stream>>>(z, gz, bz, ws);
    k_logits <<<dim3(96, 24), 256, 0, stream>>>(smask, idx, ws);
    k_softmax<<<9216, 192, 0, stream>>>(ws);
    k_ov     <<<dim3(12, 24, 3), 256, 0, stream>>>(ws);
    k_opair  <<<dim3(768, 6), 384, 0, stream>>>(idx, ws);
    k_ptfin  <<<768, 96, 0, stream>>>(rot, trans, ws);
    k_out    <<<dim3(24, 3, 4), 256, 0, stream>>>(Wout, Woutb, Woutp, ws, out);
}

// Round 3
// 793.432 us; speedup vs baseline: 1.2840x; 1.0214x over previous
//
#include <hip/hip_runtime.h>
#include <hip/hip_bf16.h>

#define NN 768
#define NSQ (768*768)
#define CS 384
#define CZ 128
#define HH 12
#define INF_ 1e5f
#define EPS_ 1e-8f
#define LN_EPS_ 1e-5f

typedef __attribute__((ext_vector_type(8))) short short8;
typedef __attribute__((ext_vector_type(4))) short short4_t;
typedef __attribute__((ext_vector_type(4))) float floatx4;

// ---- workspace layout (float element offsets) ----
constexpr size_t OFF_SLN  = 0;                           // 768*384 (unused now, kept for layout stability)
constexpr size_t OFF_PROJ = OFF_SLN + (size_t)768*384;   // 768*1152 : [q|k|v|qp|kp|vp]
constexpr size_t OFF_QPG  = OFF_PROJ + (size_t)768*1152; // 768*144
constexpr size_t OFF_KPG  = OFF_QPG + (size_t)768*144;   // 768*144
constexpr size_t OFF_VPG  = OFF_KPG + (size_t)768*144;   // 768*288
constexpr size_t OFF_WTBF = OFF_VPG + (size_t)768*288;   // 48*128 bf16
constexpr size_t OFF_HW   = OFF_WTBF + 4096;             // 16
constexpr size_t OFF_BIAS = OFF_HW + 16;                 // NSQ*12 bf16  (= NSQ*6 floats)
constexpr size_t OFF_ATT  = OFF_BIAS + (size_t)NSQ*6;    // 12*NSQ floats (logits -> probs in place)
constexpr size_t OFF_PZ   = OFF_ATT + (size_t)12*NSQ;    // NSQ*32 bf16  (= NSQ*16 floats)
constexpr size_t OFF_OCAT = OFF_PZ + (size_t)NSQ*16;     // 768*960

__device__ __forceinline__ unsigned short f2bf(float f){
    unsigned int u = __float_as_uint(f);
    u = (u + 0x7fffu + ((u >> 16) & 1u)) >> 16;
    return (unsigned short)u;
}
__device__ __forceinline__ float bf2f(unsigned short u){
    return __uint_as_float((unsigned int)u << 16);
}

// ---- K0: zero ocat + zero out + bf16 W^T + softplus(head_weights)
__global__ __launch_bounds__(256) void k_setup(const float* __restrict__ Wb, const float* __restrict__ Wdz,
                                               const float* __restrict__ hwin, float* __restrict__ ws,
                                               float* __restrict__ out){
    int b = blockIdx.x, t = threadIdx.x;
    if (b < 2880){ ws[OFF_OCAT + (size_t)b*256 + t] = 0.f; return; }
    b -= 2880;
    if (b < 1152){ out[(size_t)b*256 + t] = 0.f; return; }
    b -= 1152;
    if (b < 24){
        unsigned short* wt = (unsigned short*)(ws + OFF_WTBF);
        int o = b*2 + (t>>7), k = t & 127;
        float v = 0.f;
        if (o < HH) v = Wb[k*HH + o];
        else if (o < 44) v = Wdz[k*32 + (o - HH)];
        wt[o*128 + k] = f2bf(v);
        return;
    }
    b -= 24;
    if (b == 0 && t < HH){
        ws[OFF_HW + t] = log1pf(expf(hwin[t])) * sqrtf(1.0f/54.0f);
    }
}

// ---- K2: LN(s) fused + projections, (768x384) @ W (384x1152)
__global__ __launch_bounds__(256) void k_proj(const float* __restrict__ s, const float* __restrict__ gs,
                                              const float* __restrict__ bs,
                                              const float* __restrict__ Wq, const float* __restrict__ Wk,
                                              const float* __restrict__ Wv, const float* __restrict__ Wqp,
                                              const float* __restrict__ Wkp, const float* __restrict__ Wvp,
                                              float* __restrict__ ws){
    __shared__ float slds[16][CS];
    __shared__ float stats[16][2];
    int rt = blockIdx.x, ct = blockIdx.y, t = threadIdx.x;
    for (int ix = t; ix < 16*CS; ix += 256){
        int r = ix / CS, c = ix % CS;
        slds[r][c] = s[(size_t)(rt*16 + r)*CS + c];
    }
    __syncthreads();
    // per-row LN stats: wave w handles rows w, w+4, w+8, w+12
    int w = t >> 6, lane = t & 63;
    for (int r = w; r < 16; r += 4){
        float sum = 0.f, sq = 0.f;
        #pragma unroll
        for (int c0 = 0; c0 < CS; c0 += 64){
            float x = slds[r][c0 + lane];
            sum += x; sq += x*x;
        }
        #pragma unroll
        for (int off = 32; off; off >>= 1){
            sum += __shfl_xor(sum, off, 64);
            sq  += __shfl_xor(sq , off, 64);
        }
        if (lane == 0){
            float mu = sum * (1.0f/CS);
            float var = sq * (1.0f/CS) - mu*mu;
            stats[r][0] = mu;
            stats[r][1] = rsqrtf(var + LN_EPS_);
        }
    }
    __syncthreads();
    for (int ix = t; ix < 16*CS; ix += 256){
        int r = ix / CS, c = ix % CS;
        slds[r][c] = (slds[r][c] - stats[r][0]) * stats[r][1] * gs[c] + bs[c];
    }
    __syncthreads();
    int col = ct*128 + (t & 127);
    int rg = t >> 7;
    const float* wp; int stride;
    if      (col < 192){ wp = Wq  + col;       stride = 192; }
    else if (col < 384){ wp = Wk  + (col-192); stride = 192; }
    else if (col < 576){ wp = Wv  + (col-384); stride = 192; }
    else if (col < 720){ wp = Wqp + (col-576); stride = 144; }
    else if (col < 864){ wp = Wkp + (col-720); stride = 144; }
    else               { wp = Wvp + (col-864); stride = 288; }
    float acc[8] = {0,0,0,0,0,0,0,0};
    for (int k = 0; k < CS; k += 4){
        float w0 = wp[(size_t)k*stride];
        float w1 = wp[(size_t)(k+1)*stride];
        float w2 = wp[(size_t)(k+2)*stride];
        float w3 = wp[(size_t)(k+3)*stride];
        #pragma unroll
        for (int r = 0; r < 8; r++){
            floatx4 sv = *(const floatx4*)&slds[rg*8+r][k];
            acc[r] += sv[0]*w0 + sv[1]*w1 + sv[2]*w2 + sv[3]*w3;
        }
    }
    float* proj = ws + OFF_PROJ;
    for (int r = 0; r < 8; r++) proj[(size_t)(rt*16 + rg*8 + r)*1152 + col] = acc[r];
}

// ---- K2b: points to global frame
__global__ __launch_bounds__(192) void k_pts(const float* __restrict__ rot, const float* __restrict__ trans,
                                             float* __restrict__ ws){
    int i = blockIdx.x, p = threadIdx.x;
    const float* proj = ws + OFF_PROJ + (size_t)i*1152;
    const float* src; float* dst;
    if (p < 48)      { src = proj + 576 + p*3;       dst = ws + OFF_QPG + (size_t)i*144 + p*3; }
    else if (p < 96) { src = proj + 720 + (p-48)*3;  dst = ws + OFF_KPG + (size_t)i*144 + (p-48)*3; }
    else             { src = proj + 864 + (p-96)*3;  dst = ws + OFF_VPG + (size_t)i*288 + (p-96)*3; }
    float x = src[0], y = src[1], z = src[2];
    const float* R = rot + (size_t)i*9;
    const float* T = trans + (size_t)i*3;
    dst[0] = R[0]*x + R[1]*y + R[2]*z + T[0];
    dst[1] = R[3]*x + R[4]*y + R[5]*z + T[1];
    dst[2] = R[6]*x + R[7]*y + R[8]*z + T[2];
}

// ---- K3: LN(z) + [Wb|Wdz] via bf16 MFMA; bias & pz bf16, coalesced stores via LDS stage
__global__ __launch_bounds__(256) void k_z(const float* __restrict__ z, const float* __restrict__ gz,
                                           const float* __restrict__ bz, float* __restrict__ ws){
    __shared__ unsigned short zlds[64][136];
    int t = threadIdx.x;
    int pb = blockIdx.x * 64;
    int lane32 = t & 31;
    int col = lane32 * 4;
    floatx4 g4 = *(const floatx4*)(gz + col);
    floatx4 b4 = *(const floatx4*)(bz + col);
    const float* zbase = z + (size_t)pb * 128;
    #pragma unroll
    for (int g = 0; g < 8; g++){
        int row = g*8 + (t >> 5);
        floatx4 v = *(const floatx4*)(zbase + (size_t)g*1024 + (size_t)t*4);
        float sum = v[0]+v[1]+v[2]+v[3];
        float sq  = v[0]*v[0]+v[1]*v[1]+v[2]*v[2]+v[3]*v[3];
        #pragma unroll
        for (int off = 1; off <= 16; off <<= 1){
            sum += __shfl_xor(sum, off, 64);
            sq  += __shfl_xor(sq , off, 64);
        }
        float mu = sum * (1.0f/128.0f);
        float rstd = rsqrtf(sq*(1.0f/128.0f) - mu*mu + LN_EPS_);
        short4_t sv;
        sv[0] = (short)f2bf((v[0]-mu)*rstd*g4[0] + b4[0]);
        sv[1] = (short)f2bf((v[1]-mu)*rstd*g4[1] + b4[1]);
        sv[2] = (short)f2bf((v[2]-mu)*rstd*g4[2] + b4[2]);
        sv[3] = (short)f2bf((v[3]-mu)*rstd*g4[3] + b4[3]);
        *(short4_t*)&zlds[row][col] = sv;
    }
    __syncthreads();
    const unsigned short* wt = (const unsigned short*)(ws + OFF_WTBF);
    int lane = t & 63, wv = t >> 6;
    int m = lane & 15, quad = lane >> 4;
    short8 bfrag[3][4];
    #pragma unroll
    for (int ot = 0; ot < 3; ot++)
        #pragma unroll
        for (int ks = 0; ks < 4; ks++){
            int o = ot*16 + m;
            bfrag[ot][ks] = *(const short8*)(wt + o*128 + ks*32 + quad*8);
        }
    floatx4 acc[3] = {{0.f,0.f,0.f,0.f},{0.f,0.f,0.f,0.f},{0.f,0.f,0.f,0.f}};
    int rbase = wv*16;
    #pragma unroll
    for (int ks = 0; ks < 4; ks++){
        short8 a = *(const short8*)&zlds[rbase + m][ks*32 + quad*8];
        acc[0] = __builtin_amdgcn_mfma_f32_16x16x32_bf16(a, bfrag[0][ks], acc[0], 0, 0, 0);
        acc[1] = __builtin_amdgcn_mfma_f32_16x16x32_bf16(a, bfrag[1][ks], acc[1], 0, 0, 0);
        acc[2] = __builtin_amdgcn_mfma_f32_16x16x32_bf16(a, bfrag[2][ks], acc[2], 0, 0, 0);
    }
    // stage results in LDS (reuse zlds), then coalesced global writes
    __syncthreads();
    unsigned short* stb = &zlds[0][0];          // [64][12]  rp-major
    unsigned short* stp = &zlds[0][0] + 64*12;  // [64][32]  rp-major
    #pragma unroll
    for (int ot = 0; ot < 3; ot++){
        int o = ot*16 + m;
        #pragma unroll
        for (int rg = 0; rg < 4; rg++){
            int rp = rbase + quad*4 + rg;
            float val = acc[ot][rg];
            if (o < HH)      stb[rp*12 + o] = f2bf(val);
            else if (o < 44) stp[rp*32 + (o - HH)] = f2bf(val);
        }
    }
    __syncthreads();
    unsigned short* bias16 = (unsigned short*)(ws + OFF_BIAS);
    unsigned int*   pz32   = (unsigned int*)((unsigned short*)(ws + OFF_PZ));
    for (int ix = t; ix < 12*32; ix += 256){
        int o = ix >> 5, u = ix & 31;
        unsigned int val = (unsigned int)stb[(u*2)*12 + o] | ((unsigned int)stb[(u*2+1)*12 + o] << 16);
        *(unsigned int*)(bias16 + (size_t)o*NSQ + pb + u*2) = val;
    }
    for (int ix = t; ix < 64*16; ix += 256){
        int rp = ix >> 4, u = ix & 15;
        unsigned int val = (unsigned int)stp[rp*32 + u*2] | ((unsigned int)stp[rp*32 + u*2+1] << 16);
        pz32[(size_t)(pb + rp)*16 + u] = val;
    }
}

// ---- K4: logits (bias read from bf16 buffer)
__global__ __launch_bounds__(256) void k_logits(const float* __restrict__ smask, const int* __restrict__ idx,
                                                float* __restrict__ ws){
    __shared__ float qlds[8][336];
    __shared__ float klds[32][338];
    int it = blockIdx.x, jt = blockIdx.y, t = threadIdx.x;
    const float* proj = ws + OFF_PROJ;
    const float* qpg  = ws + OFF_QPG;
    const float* kpg  = ws + OFF_KPG;
    const float* hw   = ws + OFF_HW;
    const unsigned short* bias16 = (const unsigned short*)(ws + OFF_BIAS);
    float* att = ws + OFF_ATT;
    for (int ix = t; ix < 8*336; ix += 256){
        int r = ix / 336, c = ix % 336;
        int i = it*8 + r;
        qlds[r][c] = (c < 192) ? proj[(size_t)i*1152 + c] : qpg[(size_t)i*144 + (c - 192)];
    }
    for (int ix = t; ix < 32*336; ix += 256){
        int r = ix / 336, c = ix % 336;
        int j = jt*32 + r;
        klds[r][c] = (c < 192) ? proj[(size_t)j*1152 + 192 + c] : kpg[(size_t)j*144 + (c - 192)];
    }
    __syncthreads();
    int jl = t & 31, grp = t >> 5;
    int i = it*8 + grp, j = jt*32 + jl;
    int ires = idx[i], jres = idx[j];
    float mterm = INF_ * (smask[ires]*smask[jres] - 1.0f);
    const float S1 = 0.14433756729740643f;
    const float S2 = 0.57735026918962576f;
    for (int h = 0; h < HH; h++){
        floatx4 q0 = *(const floatx4*)&qlds[grp][h*16];
        floatx4 q1 = *(const floatx4*)&qlds[grp][h*16+4];
        floatx4 q2 = *(const floatx4*)&qlds[grp][h*16+8];
        floatx4 q3 = *(const floatx4*)&qlds[grp][h*16+12];
        const float* kr = &klds[jl][h*16];
        float2 k0 = *(const float2*)(kr+0),  k1 = *(const float2*)(kr+2);
        float2 k2 = *(const float2*)(kr+4),  k3 = *(const float2*)(kr+6);
        float2 k4 = *(const float2*)(kr+8),  k5 = *(const float2*)(kr+10);
        float2 k6 = *(const float2*)(kr+12), k7 = *(const float2*)(kr+14);
        float qk = q0[0]*k0.x+q0[1]*k0.y+q0[2]*k1.x+q0[3]*k1.y
                 + q1[0]*k2.x+q1[1]*k2.y+q1[2]*k3.x+q1[3]*k3.y
                 + q2[0]*k4.x+q2[1]*k4.y+q2[2]*k5.x+q2[3]*k5.y
                 + q3[0]*k6.x+q3[1]*k6.y+q3[2]*k7.x+q3[3]*k7.y;
        floatx4 qp0 = *(const floatx4*)&qlds[grp][192+h*12];
        floatx4 qp1 = *(const floatx4*)&qlds[grp][192+h*12+4];
        floatx4 qp2 = *(const floatx4*)&qlds[grp][192+h*12+8];
        const float* kp = &klds[jl][192+h*12];
        float2 p0 = *(const float2*)(kp+0), p1 = *(const float2*)(kp+2);
        float2 p2 = *(const float2*)(kp+4), p3 = *(const float2*)(kp+6);
        float2 p4 = *(const float2*)(kp+8), p5 = *(const float2*)(kp+10);
        float d0 = qp0[0]-p0.x, d1 = qp0[1]-p0.y, d2a = qp0[2]-p1.x, d3 = qp0[3]-p1.y;
        float d4 = qp1[0]-p2.x, d5 = qp1[1]-p2.y, d6 = qp1[2]-p3.x, d7 = qp1[3]-p3.y;
        float d8 = qp2[0]-p4.x, d9 = qp2[1]-p4.y, dA = qp2[2]-p5.x, dB = qp2[3]-p5.y;
        float d2 = d0*d0+d1*d1+d2a*d2a+d3*d3 + d4*d4+d5*d5+d6*d6+d7*d7 + d8*d8+d9*d9+dA*dA+dB*dB;
        float bv = bf2f(bias16[(size_t)h*NSQ + (size_t)ires*NN + jres]);
        float lg = qk*S1 + S2*(bv + mterm) - 0.5f*hw[h]*d2;
        att[(size_t)h*NSQ + (size_t)i*NN + j] = lg;
    }
}

// ---- K4c: softmax, one wave per row, no LDS / no barriers
__global__ __launch_bounds__(256) void k_softmax(float* __restrict__ ws){
    int t = threadIdx.x;
    int w = t >> 6, lane = t & 63;
    size_t rowi = (size_t)blockIdx.x*4 + w;
    float* row = ws + OFF_ATT + rowi*NN;
    floatx4 v0 = *(floatx4*)(row + lane*4);
    floatx4 v1 = *(floatx4*)(row + 256 + lane*4);
    floatx4 v2 = *(floatx4*)(row + 512 + lane*4);
    float mx = fmaxf(fmaxf(fmaxf(v0[0],v0[1]), fmaxf(v0[2],v0[3])),
               fmaxf(fmaxf(fmaxf(v1[0],v1[1]), fmaxf(v1[2],v1[3])),
                     fmaxf(fmaxf(v2[0],v2[1]), fmaxf(v2[2],v2[3]))));
    #pragma unroll
    for (int off = 32; off; off >>= 1) mx = fmaxf(mx, __shfl_xor(mx, off, 64));
    floatx4 e0, e1, e2;
    #pragma unroll
    for (int u = 0; u < 4; u++){ e0[u] = expf(v0[u]-mx); e1[u] = expf(v1[u]-mx); e2[u] = expf(v2[u]-mx); }
    float s = e0[0]+e0[1]+e0[2]+e0[3] + e1[0]+e1[1]+e1[2]+e1[3] + e2[0]+e2[1]+e2[2]+e2[3];
    #pragma unroll
    for (int off = 32; off; off >>= 1) s += __shfl_xor(s, off, 64);
    float inv = 1.0f / s;
    #pragma unroll
    for (int u = 0; u < 4; u++){ e0[u] *= inv; e1[u] *= inv; e2[u] *= inv; }
    *(floatx4*)(row + lane*4) = e0;
    *(floatx4*)(row + 256 + lane*4) = e1;
    *(floatx4*)(row + 512 + lane*4) = e2;
}

// ---- K5: o and o_pt(global), j-split x3, atomic accumulate
__global__ __launch_bounds__(256) void k_ov(float* __restrict__ ws){
    __shared__ float wlds[128][41];
    __shared__ float plds[32][128];
    int h = blockIdx.x, it = blockIdx.y, zs = blockIdx.z, t = threadIdx.x;
    const float* proj = ws + OFF_PROJ;
    const float* vpg  = ws + OFF_VPG;
    const float* att  = ws + OFF_ATT + (size_t)h*NSQ;
    int c = t & 63, isub = t >> 6;
    float acc[8] = {0,0,0,0,0,0,0,0};
    for (int jt = zs*2; jt < zs*2+2; jt++){
        __syncthreads();
        for (int ix = t; ix < 128*40; ix += 256){
            int jj = ix / 40, cc = ix % 40;
            int j = jt*128 + jj;
            wlds[jj][cc] = (cc < 16) ? proj[(size_t)j*1152 + 384 + h*16 + cc]
                                     : vpg[(size_t)j*288 + h*24 + (cc - 16)];
        }
        for (int ix = t; ix < 32*128; ix += 256){
            int rr = ix >> 7, jj = ix & 127;
            plds[rr][jj] = att[(size_t)(it*32 + rr)*NN + jt*128 + jj];
        }
        __syncthreads();
        if (c < 40){
            for (int jj = 0; jj < 128; jj += 4){
                float w0 = wlds[jj][c], w1 = wlds[jj+1][c], w2 = wlds[jj+2][c], w3 = wlds[jj+3][c];
                #pragma unroll
                for (int rr = 0; rr < 8; rr++){
                    floatx4 pv = *(floatx4*)&plds[isub*8+rr][jj];
                    acc[rr] += pv[0]*w0 + pv[1]*w1 + pv[2]*w2 + pv[3]*w3;
                }
            }
        }
    }
    if (c < 40){
        float* ocat = ws + OFF_OCAT;
        int col = (c < 16) ? (h*16 + c) : (576 + h*24 + (c - 16));
        for (int rr = 0; rr < 8; rr++){
            int i = it*32 + isub*8 + rr;
            atomicAdd(&ocat[(size_t)i*960 + col], acc[rr]);
        }
    }
}

// ---- K6: o_pair: grid (i, jt). pz bf16.
__global__ __launch_bounds__(384) void k_opair(const int* __restrict__ idx, float* __restrict__ ws){
    __shared__ float plds[12][132];
    __shared__ float pzlds[128][33];
    int i = blockIdx.x, jt = blockIdx.y, t = threadIdx.x;
    int ires = idx[i];
    const unsigned int* pzg = (const unsigned int*)((const unsigned short*)(ws + OFF_PZ) + (size_t)ires*NN*32);
    const float* att = ws + OFF_ATT;
    for (int ix = t; ix < 12*128; ix += 384){
        int hh = ix >> 7, jj = ix & 127;
        plds[hh][jj] = att[(size_t)hh*NSQ + (size_t)i*NN + jt*128 + jj];
    }
    for (int ix = t; ix < 128*16; ix += 384){
        int jj = ix >> 4, cp = ix & 15;
        int jres = idx[jt*128 + jj];
        unsigned int u2 = pzg[(size_t)jres*16 + cp];
        pzlds[jj][cp*2]   = __uint_as_float(u2 << 16);
        pzlds[jj][cp*2+1] = __uint_as_float(u2 & 0xffff0000u);
    }
    __syncthreads();
    int h = t >> 5, c = t & 31;
    float acc = 0.f;
    #pragma unroll 4
    for (int j = 0; j < 128; j++)
        acc += plds[h][j] * pzlds[j][c];
    float* oc = ws + OFF_OCAT + (size_t)i*960 + 192;
    atomicAdd(&oc[h*32 + c], acc);
}

// ---- K6b: o_pt local frame + norms
__global__ __launch_bounds__(96) void k_ptfin(const float* __restrict__ rot, const float* __restrict__ trans,
                                              float* __restrict__ ws){
    int i = blockIdx.x, p = threadIdx.x;
    float* base = ws + OFF_OCAT + (size_t)i*960;
    float* pt = base + 576 + p*3;
    float x = pt[0] - trans[i*3+0];
    float y = pt[1] - trans[i*3+1];
    float z = pt[2] - trans[i*3+2];
    const float* R = rot + (size_t)i*9;
    float lx = R[0]*x + R[3]*y + R[6]*z;
    float ly = R[1]*x + R[4]*y + R[7]*z;
    float lz = R[2]*x + R[5]*y + R[8]*z;
    pt[0] = lx; pt[1] = ly; pt[2] = lz;
    base[864 + p] = sqrtf(lx*lx + ly*ly + lz*lz + EPS_);
}

// ---- K7: final GEMM, k-split x4, 8x2 register tile, atomic into zeroed out
__global__ __launch_bounds__(256) void k_out(const float* __restrict__ Wout, const float* __restrict__ Woutb,
                                             const float* __restrict__ Woutp, float* __restrict__ ws,
                                             float* __restrict__ out){
    __shared__ float olds[32][244];
    int it = blockIdx.x, ct = blockIdx.y, kc = blockIdx.z, t = threadIdx.x;
    const float* ocat = ws + OFF_OCAT;
    for (int ix = t; ix < 32*240; ix += 256){
        int r = ix / 240, kk = ix % 240;
        olds[r][kk] = ocat[(size_t)(it*32 + r)*960 + kc*240 + kk];
    }
    __syncthreads();
    int cl = t & 63, ig = t >> 6;
    int c0 = ct*128 + cl, c1 = c0 + 64;
    float acc0[8], acc1[8];
    #pragma unroll
    for (int r=0;r<8;r++){ acc0[r]=0; acc1[r]=0; }
    for (int kk = 0; kk < 240; kk += 4){
        float w0[4], w1[4];
        #pragma unroll
        for (int u = 0; u < 4; u++){
            int k = kc*240 + kk + u;
            const float* wrow = (k < 192) ? (Wout  + (size_t)k*CS)
                              : (k < 576) ? (Woutb + (size_t)(k-192)*CS)
                                          : (Woutp + (size_t)(k-576)*CS);
            w0[u] = wrow[c0]; w1[u] = wrow[c1];
        }
        #pragma unroll
        for (int r = 0; r < 8; r++){
            floatx4 ov = *(const floatx4*)&olds[ig*8 + r][kk];
            acc0[r] += ov[0]*w0[0] + ov[1]*w0[1] + ov[2]*w0[2] + ov[3]*w0[3];
            acc1[r] += ov[0]*w1[0] + ov[1]*w1[1] + ov[2]*w1[2] + ov[3]*w1[3];
        }
    }
    for (int r = 0; r < 8; r++){
        int i = it*32 + ig*8 + r;
        atomicAdd(&out[(size_t)i*CS + c0], acc0[r]);
        atomicAdd(&out[(size_t)i*CS + c1], acc1[r]);
    }
}

extern "C" void kernel_launch(void* const* d_in, const int* in_sizes, int n_in,
                              void* d_out, int out_size, void* d_ws, size_t ws_size,
                              hipStream_t stream){
    const float* s     = (const float*)d_in[0];
    const float* z     = (const float*)d_in[1];
    const float* rot   = (const float*)d_in[2];
    const float* trans = (const float*)d_in[3];
    const float* smask = (const float*)d_in[4];
    const float* gs    = (const float*)d_in[5];
    const float* bs    = (const float*)d_in[6];
    const float* gz    = (const float*)d_in[7];
    const float* bz    = (const float*)d_in[8];
    const float* Wq    = (const float*)d_in[9];
    const float* Wk    = (const float*)d_in[10];
    const float* Wv    = (const float*)d_in[11];
    const float* Wqp   = (const float*)d_in[12];
    const float* Wkp   = (const float*)d_in[13];
    const float* Wvp   = (const float*)d_in[14];
    const float* Wb    = (const float*)d_in[15];
    const float* Wdz   = (const float*)d_in[16];
    const float* hwin  = (const float*)d_in[17];
    const float* Wout  = (const float*)d_in[18];
    const float* Woutb = (const float*)d_in[19];
    const float* Woutp = (const float*)d_in[20];
    const int*   idx   = (const int*)d_in[21];
    float* ws  = (float*)d_ws;
    float* out = (float*)d_out;

    k_setup  <<<4057, 256, 0, stream>>>(Wb, Wdz, hwin, ws, out);
    k_proj   <<<dim3(48, 9), 256, 0, stream>>>(s, gs, bs, Wq, Wk, Wv, Wqp, Wkp, Wvp, ws);
    k_pts    <<<768, 192, 0, stream>>>(rot, trans, ws);
    k_z      <<<9216, 256, 0, stream>>>(z, gz, bz, ws);
    k_logits <<<dim3(96, 24), 256, 0, stream>>>(smask, idx, ws);
    k_softmax<<<2304, 256, 0, stream>>>(ws);
    k_ov     <<<dim3(12, 24, 3), 256, 0, stream>>>(ws);
    k_opair  <<<dim3(768, 6), 384, 0, stream>>>(idx, ws);
    k_ptfin  <<<768, 96, 0, stream>>>(rot, trans, ws);
    k_out    <<<dim3(24, 3, 4), 256, 0, stream>>>(Wout, Woutb, Woutp, ws, out);
}

// Round 4
// 693.516 us; speedup vs baseline: 1.4690x; 1.1441x over previous
//
#include <hip/hip_runtime.h>
#include <hip/hip_bf16.h>

#define NN 768
#define NSQ (768*768)
#define CS 384
#define CZ 128
#define HH 12
#define INF_ 1e5f
#define EPS_ 1e-8f
#define LN_EPS_ 1e-5f

typedef __attribute__((ext_vector_type(8))) short short8;
typedef __attribute__((ext_vector_type(4))) short short4_t;
typedef __attribute__((ext_vector_type(4))) float floatx4;

// ---- workspace layout (float element offsets) ----
constexpr size_t OFF_SLN  = 0;                           // 768*384 (unused, layout stability)
constexpr size_t OFF_PROJ = OFF_SLN + (size_t)768*384;   // 768*1152 : [q|k|v|qp|kp|vp]
constexpr size_t OFF_QPG  = OFF_PROJ + (size_t)768*1152; // 768*144
constexpr size_t OFF_KPG  = OFF_QPG + (size_t)768*144;   // 768*144
constexpr size_t OFF_VPG  = OFF_KPG + (size_t)768*144;   // 768*288
constexpr size_t OFF_WTBF = OFF_VPG + (size_t)768*288;   // 48*128 bf16
constexpr size_t OFF_HW   = OFF_WTBF + 4096;             // 16
constexpr size_t OFF_BIAS = OFF_HW + 16;                 // NSQ*12 bf16  (= NSQ*6 floats)
constexpr size_t OFF_ATT  = OFF_BIAS + (size_t)NSQ*6;    // 12*NSQ floats (logits -> probs in place)
constexpr size_t OFF_PZ   = OFF_ATT + (size_t)12*NSQ;    // NSQ*32 bf16  (= NSQ*16 floats)
constexpr size_t OFF_OCAT = OFF_PZ + (size_t)NSQ*16;     // 768*960
constexpr size_t OFF_ABF  = OFF_OCAT + (size_t)768*960;  // 12*768*64 bf16 = 294912 floats
constexpr size_t OFF_BBF  = OFF_ABF + 294912;            // 12*768*64 bf16
constexpr size_t OFF_CJ   = OFF_BBF + 294912;            // 12*768 floats

__device__ __forceinline__ unsigned short f2bf(float f){
    unsigned int u = __float_as_uint(f);
    u = (u + 0x7fffu + ((u >> 16) & 1u)) >> 16;
    return (unsigned short)u;
}
__device__ __forceinline__ float bf2f(unsigned short u){
    return __uint_as_float((unsigned int)u << 16);
}

// ---- K0: zero ocat + zero out + bf16 W^T + softplus(head_weights)
__global__ __launch_bounds__(256) void k_setup(const float* __restrict__ Wb, const float* __restrict__ Wdz,
                                               const float* __restrict__ hwin, float* __restrict__ ws,
                                               float* __restrict__ out){
    int b = blockIdx.x, t = threadIdx.x;
    if (b < 2880){ ws[OFF_OCAT + (size_t)b*256 + t] = 0.f; return; }
    b -= 2880;
    if (b < 1152){ out[(size_t)b*256 + t] = 0.f; return; }
    b -= 1152;
    if (b < 24){
        unsigned short* wt = (unsigned short*)(ws + OFF_WTBF);
        int o = b*2 + (t>>7), k = t & 127;
        float v = 0.f;
        if (o < HH) v = Wb[k*HH + o];
        else if (o < 44) v = Wdz[k*32 + (o - HH)];
        wt[o*128 + k] = f2bf(v);
        return;
    }
    b -= 24;
    if (b == 0 && t < HH){
        ws[OFF_HW + t] = log1pf(expf(hwin[t])) * sqrtf(1.0f/54.0f);
    }
}

// ---- K2: LN(s) fused + projections, (768x384) @ W (384x1152)
__global__ __launch_bounds__(256) void k_proj(const float* __restrict__ s, const float* __restrict__ gs,
                                              const float* __restrict__ bs,
                                              const float* __restrict__ Wq, const float* __restrict__ Wk,
                                              const float* __restrict__ Wv, const float* __restrict__ Wqp,
                                              const float* __restrict__ Wkp, const float* __restrict__ Wvp,
                                              float* __restrict__ ws){
    __shared__ float slds[16][CS];
    __shared__ float stats[16][2];
    int rt = blockIdx.x, ct = blockIdx.y, t = threadIdx.x;
    for (int ix = t; ix < 16*CS; ix += 256){
        int r = ix / CS, c = ix % CS;
        slds[r][c] = s[(size_t)(rt*16 + r)*CS + c];
    }
    __syncthreads();
    int w = t >> 6, lane = t & 63;
    for (int r = w; r < 16; r += 4){
        float sum = 0.f, sq = 0.f;
        #pragma unroll
        for (int c0 = 0; c0 < CS; c0 += 64){
            float x = slds[r][c0 + lane];
            sum += x; sq += x*x;
        }
        #pragma unroll
        for (int off = 32; off; off >>= 1){
            sum += __shfl_xor(sum, off, 64);
            sq  += __shfl_xor(sq , off, 64);
        }
        if (lane == 0){
            float mu = sum * (1.0f/CS);
            float var = sq * (1.0f/CS) - mu*mu;
            stats[r][0] = mu;
            stats[r][1] = rsqrtf(var + LN_EPS_);
        }
    }
    __syncthreads();
    for (int ix = t; ix < 16*CS; ix += 256){
        int r = ix / CS, c = ix % CS;
        slds[r][c] = (slds[r][c] - stats[r][0]) * stats[r][1] * gs[c] + bs[c];
    }
    __syncthreads();
    int col = ct*128 + (t & 127);
    int rg = t >> 7;
    const float* wp; int stride;
    if      (col < 192){ wp = Wq  + col;       stride = 192; }
    else if (col < 384){ wp = Wk  + (col-192); stride = 192; }
    else if (col < 576){ wp = Wv  + (col-384); stride = 192; }
    else if (col < 720){ wp = Wqp + (col-576); stride = 144; }
    else if (col < 864){ wp = Wkp + (col-720); stride = 144; }
    else               { wp = Wvp + (col-864); stride = 288; }
    float acc[8] = {0,0,0,0,0,0,0,0};
    for (int k = 0; k < CS; k += 4){
        float w0 = wp[(size_t)k*stride];
        float w1 = wp[(size_t)(k+1)*stride];
        float w2 = wp[(size_t)(k+2)*stride];
        float w3 = wp[(size_t)(k+3)*stride];
        #pragma unroll
        for (int r = 0; r < 8; r++){
            floatx4 sv = *(const floatx4*)&slds[rg*8+r][k];
            acc[r] += sv[0]*w0 + sv[1]*w1 + sv[2]*w2 + sv[3]*w3;
        }
    }
    float* proj = ws + OFF_PROJ;
    for (int r = 0; r < 8; r++) proj[(size_t)(rt*16 + rg*8 + r)*1152 + col] = acc[r];
}

// ---- K2b: points to global frame
__global__ __launch_bounds__(192) void k_pts(const float* __restrict__ rot, const float* __restrict__ trans,
                                             float* __restrict__ ws){
    int i = blockIdx.x, p = threadIdx.x;
    const float* proj = ws + OFF_PROJ + (size_t)i*1152;
    const float* src; float* dst;
    if (p < 48)      { src = proj + 576 + p*3;       dst = ws + OFF_QPG + (size_t)i*144 + p*3; }
    else if (p < 96) { src = proj + 720 + (p-48)*3;  dst = ws + OFF_KPG + (size_t)i*144 + (p-48)*3; }
    else             { src = proj + 864 + (p-96)*3;  dst = ws + OFF_VPG + (size_t)i*288 + (p-96)*3; }
    float x = src[0], y = src[1], z = src[2];
    const float* R = rot + (size_t)i*9;
    const float* T = trans + (size_t)i*3;
    dst[0] = R[0]*x + R[1]*y + R[2]*z + T[0];
    dst[1] = R[3]*x + R[4]*y + R[5]*z + T[1];
    dst[2] = R[6]*x + R[7]*y + R[8]*z + T[2];
}

// ---- K2c: build bf16 feature matrices for logits GEMM
// A = [q | qp_hi | qp_lo | qp_hi | 0], B = [S1*k | x_hi | x_hi | x_lo | 0], x = hw*kp (limb-split)
// dot(A,B) = S1*(q.k) + hw*(qp.kp) (error ~ qp_lo*x_lo, negligible)
// Cj[h][j] = -0.5*hw*|kp_j|^2
__global__ __launch_bounds__(256) void k_feat(float* __restrict__ ws){
    int i = blockIdx.x, t = threadIdx.x;
    const float* proj = ws + OFF_PROJ + (size_t)i*1152;
    const float* qpg  = ws + OFF_QPG + (size_t)i*144;
    const float* kpg  = ws + OFF_KPG + (size_t)i*144;
    unsigned short* Abf = (unsigned short*)(ws + OFF_ABF);
    unsigned short* Bbf = (unsigned short*)(ws + OFF_BBF);
    const float S1 = 0.14433756729740643f;
    for (int ix = t; ix < 12*64; ix += 256){
        int h = ix >> 6, c = ix & 63;
        float hwv = ws[OFF_HW + h];
        unsigned short ab = 0, bb = 0;
        if (c < 16){
            ab = f2bf(proj[h*16 + c]);
            bb = f2bf(S1 * proj[192 + h*16 + c]);
        } else if (c < 28){
            int d = c - 16;
            ab = f2bf(qpg[h*12 + d]);                    // qp_hi
            bb = f2bf(hwv * kpg[h*12 + d]);              // x_hi
        } else if (c < 40){
            int d = c - 28;
            float qp = qpg[h*12 + d];
            unsigned short hi = f2bf(qp);
            ab = f2bf(qp - bf2f(hi));                    // qp_lo
            bb = f2bf(hwv * kpg[h*12 + d]);              // x_hi (again)
        } else if (c < 52){
            int d = c - 40;
            ab = f2bf(qpg[h*12 + d]);                    // qp_hi (again)
            float x = hwv * kpg[h*12 + d];
            unsigned short xh = f2bf(x);
            bb = f2bf(x - bf2f(xh));                     // x_lo
        }
        Abf[((size_t)h*768 + i)*64 + c] = ab;
        Bbf[((size_t)h*768 + i)*64 + c] = bb;
    }
    if (t < 12){
        float hwv = ws[OFF_HW + t];
        float s2 = 0.f;
        #pragma unroll
        for (int d = 0; d < 12; d++){ float kp = kpg[t*12 + d]; s2 += kp*kp; }
        ws[OFF_CJ + (size_t)t*768 + i] = -0.5f * hwv * s2;
    }
}

// ---- K3: LN(z) + [Wb|Wdz] via bf16 MFMA; bias & pz bf16, coalesced stores via LDS stage
__global__ __launch_bounds__(256) void k_z(const float* __restrict__ z, const float* __restrict__ gz,
                                           const float* __restrict__ bz, float* __restrict__ ws){
    __shared__ unsigned short zlds[64][136];
    int t = threadIdx.x;
    int pb = blockIdx.x * 64;
    int lane32 = t & 31;
    int col = lane32 * 4;
    floatx4 g4 = *(const floatx4*)(gz + col);
    floatx4 b4 = *(const floatx4*)(bz + col);
    const float* zbase = z + (size_t)pb * 128;
    #pragma unroll
    for (int g = 0; g < 8; g++){
        int row = g*8 + (t >> 5);
        floatx4 v = *(const floatx4*)(zbase + (size_t)g*1024 + (size_t)t*4);
        float sum = v[0]+v[1]+v[2]+v[3];
        float sq  = v[0]*v[0]+v[1]*v[1]+v[2]*v[2]+v[3]*v[3];
        #pragma unroll
        for (int off = 1; off <= 16; off <<= 1){
            sum += __shfl_xor(sum, off, 64);
            sq  += __shfl_xor(sq , off, 64);
        }
        float mu = sum * (1.0f/128.0f);
        float rstd = rsqrtf(sq*(1.0f/128.0f) - mu*mu + LN_EPS_);
        short4_t sv;
        sv[0] = (short)f2bf((v[0]-mu)*rstd*g4[0] + b4[0]);
        sv[1] = (short)f2bf((v[1]-mu)*rstd*g4[1] + b4[1]);
        sv[2] = (short)f2bf((v[2]-mu)*rstd*g4[2] + b4[2]);
        sv[3] = (short)f2bf((v[3]-mu)*rstd*g4[3] + b4[3]);
        *(short4_t*)&zlds[row][col] = sv;
    }
    __syncthreads();
    const unsigned short* wt = (const unsigned short*)(ws + OFF_WTBF);
    int lane = t & 63, wv = t >> 6;
    int m = lane & 15, quad = lane >> 4;
    short8 bfrag[3][4];
    #pragma unroll
    for (int ot = 0; ot < 3; ot++)
        #pragma unroll
        for (int ks = 0; ks < 4; ks++){
            int o = ot*16 + m;
            bfrag[ot][ks] = *(const short8*)(wt + o*128 + ks*32 + quad*8);
        }
    floatx4 acc[3] = {{0.f,0.f,0.f,0.f},{0.f,0.f,0.f,0.f},{0.f,0.f,0.f,0.f}};
    int rbase = wv*16;
    #pragma unroll
    for (int ks = 0; ks < 4; ks++){
        short8 a = *(const short8*)&zlds[rbase + m][ks*32 + quad*8];
        acc[0] = __builtin_amdgcn_mfma_f32_16x16x32_bf16(a, bfrag[0][ks], acc[0], 0, 0, 0);
        acc[1] = __builtin_amdgcn_mfma_f32_16x16x32_bf16(a, bfrag[1][ks], acc[1], 0, 0, 0);
        acc[2] = __builtin_amdgcn_mfma_f32_16x16x32_bf16(a, bfrag[2][ks], acc[2], 0, 0, 0);
    }
    __syncthreads();
    unsigned short* stb = &zlds[0][0];
    unsigned short* stp = &zlds[0][0] + 64*12;
    #pragma unroll
    for (int ot = 0; ot < 3; ot++){
        int o = ot*16 + m;
        #pragma unroll
        for (int rg = 0; rg < 4; rg++){
            int rp = rbase + quad*4 + rg;
            float val = acc[ot][rg];
            if (o < HH)      stb[rp*12 + o] = f2bf(val);
            else if (o < 44) stp[rp*32 + (o - HH)] = f2bf(val);
        }
    }
    __syncthreads();
    unsigned short* bias16 = (unsigned short*)(ws + OFF_BIAS);
    unsigned int*   pz32   = (unsigned int*)((unsigned short*)(ws + OFF_PZ));
    for (int ix = t; ix < 12*32; ix += 256){
        int o = ix >> 5, u = ix & 31;
        unsigned int val = (unsigned int)stb[(u*2)*12 + o] | ((unsigned int)stb[(u*2+1)*12 + o] << 16);
        *(unsigned int*)(bias16 + (size_t)o*NSQ + pb + u*2) = val;
    }
    for (int ix = t; ix < 64*16; ix += 256){
        int rp = ix >> 4, u = ix & 15;
        unsigned int val = (unsigned int)stp[rp*32 + u*2] | ((unsigned int)stp[rp*32 + u*2+1] << 16);
        pz32[(size_t)(pb + rp)*16 + u] = val;
    }
}

// ---- K4: logits via MFMA. grid (12 it, 12 jt, 12 h), 64x64 tile per block.
// logit = dot(A_i,B_j) + S2*bias + si*S2*INF*(sj-1) + Cj  (row-constants dropped; softmax-invariant)
__global__ __launch_bounds__(256) void k_lg(const float* __restrict__ smask, const int* __restrict__ idx,
                                            float* __restrict__ ws){
    __shared__ unsigned short Al[64][64];
    __shared__ unsigned short Bl[64][64];
    __shared__ int   idJ[64];
    __shared__ float sIv[64];
    __shared__ float sjv[64];
    __shared__ float cjv[64];
    int it = blockIdx.x, jt = blockIdx.y, h = blockIdx.z, t = threadIdx.x;
    const unsigned int* Ag = (const unsigned int*)((const unsigned short*)(ws + OFF_ABF) + ((size_t)h*768 + it*64)*64);
    const unsigned int* Bg = (const unsigned int*)((const unsigned short*)(ws + OFF_BBF) + ((size_t)h*768 + jt*64)*64);
    // stage with 16B-granule XOR swizzle: granule g -> g ^ (row&7)
    for (int ix = t; ix < 64*32; ix += 256){
        int r = ix >> 5, u = ix & 31;
        int gs = ((u >> 2) ^ (r & 7));
        int us = (gs << 2) | (u & 3);
        ((unsigned int*)&Al[r][0])[us] = Ag[ix];
        ((unsigned int*)&Bl[r][0])[us] = Bg[ix];
    }
    if (t < 64){
        int i = it*64 + t, j = jt*64 + t;
        int ii = idx[i], jj = idx[j];
        sIv[t] = smask[ii];
        idJ[t] = jj;
        sjv[t] = INF_ * 0.57735026918962576f * (smask[jj] - 1.0f);
        cjv[t] = ws[OFF_CJ + (size_t)h*768 + j];
    }
    __syncthreads();
    int lane = t & 63, w = t >> 6;
    int m = lane & 15, quad = lane >> 4;
    short8 af0, af1;
    {
        int r = w*16 + m;
        int g0 = (quad) ^ (r & 7);
        int g1 = (quad + 4) ^ (r & 7);
        af0 = *(const short8*)&Al[r][g0*8];
        af1 = *(const short8*)&Al[r][g1*8];
    }
    floatx4 acc[4] = {{0.f,0.f,0.f,0.f},{0.f,0.f,0.f,0.f},{0.f,0.f,0.f,0.f},{0.f,0.f,0.f,0.f}};
    #pragma unroll
    for (int nt = 0; nt < 4; nt++){
        int r = nt*16 + m;
        int g0 = (quad) ^ (r & 7);
        int g1 = (quad + 4) ^ (r & 7);
        short8 bf0 = *(const short8*)&Bl[r][g0*8];
        short8 bf1 = *(const short8*)&Bl[r][g1*8];
        acc[nt] = __builtin_amdgcn_mfma_f32_16x16x32_bf16(af0, bf0, acc[nt], 0, 0, 0);
        acc[nt] = __builtin_amdgcn_mfma_f32_16x16x32_bf16(af1, bf1, acc[nt], 0, 0, 0);
    }
    // ires for the 4 output rows of this lane
    const unsigned short* bias16 = (const unsigned short*)(ws + OFF_BIAS) + (size_t)h*NSQ;
    float* att = ws + OFF_ATT + (size_t)h*NSQ;
    const float S2 = 0.57735026918962576f;
    #pragma unroll
    for (int rg = 0; rg < 4; rg++){
        int il = w*16 + quad*4 + rg;
        int i  = it*64 + il;
        int ires = idx[i];
        float si = sIv[il];
        const unsigned short* brow = bias16 + (size_t)ires*NN;
        float* arow = att + (size_t)i*NN + jt*64;
        #pragma unroll
        for (int nt = 0; nt < 4; nt++){
            int jl = nt*16 + m;
            float bv = bf2f(brow[idJ[jl]]);
            arow[jl] = acc[nt][rg] + S2*bv + si*sjv[jl] + cjv[jl];
        }
    }
}

// ---- K4c: softmax, one wave per row, no LDS / no barriers
__global__ __launch_bounds__(256) void k_softmax(float* __restrict__ ws){
    int t = threadIdx.x;
    int w = t >> 6, lane = t & 63;
    size_t rowi = (size_t)blockIdx.x*4 + w;
    float* row = ws + OFF_ATT + rowi*NN;
    floatx4 v0 = *(floatx4*)(row + lane*4);
    floatx4 v1 = *(floatx4*)(row + 256 + lane*4);
    floatx4 v2 = *(floatx4*)(row + 512 + lane*4);
    float mx = fmaxf(fmaxf(fmaxf(v0[0],v0[1]), fmaxf(v0[2],v0[3])),
               fmaxf(fmaxf(fmaxf(v1[0],v1[1]), fmaxf(v1[2],v1[3])),
                     fmaxf(fmaxf(v2[0],v2[1]), fmaxf(v2[2],v2[3]))));
    #pragma unroll
    for (int off = 32; off; off >>= 1) mx = fmaxf(mx, __shfl_xor(mx, off, 64));
    floatx4 e0, e1, e2;
    #pragma unroll
    for (int u = 0; u < 4; u++){ e0[u] = expf(v0[u]-mx); e1[u] = expf(v1[u]-mx); e2[u] = expf(v2[u]-mx); }
    float s = e0[0]+e0[1]+e0[2]+e0[3] + e1[0]+e1[1]+e1[2]+e1[3] + e2[0]+e2[1]+e2[2]+e2[3];
    #pragma unroll
    for (int off = 32; off; off >>= 1) s += __shfl_xor(s, off, 64);
    float inv = 1.0f / s;
    #pragma unroll
    for (int u = 0; u < 4; u++){ e0[u] *= inv; e1[u] *= inv; e2[u] *= inv; }
    *(floatx4*)(row + lane*4) = e0;
    *(floatx4*)(row + 256 + lane*4) = e1;
    *(floatx4*)(row + 512 + lane*4) = e2;
}

// ---- K5: o and o_pt(global), j-split x3, atomic accumulate
__global__ __launch_bounds__(256) void k_ov(float* __restrict__ ws){
    __shared__ float wlds[128][41];
    __shared__ float plds[32][128];
    int h = blockIdx.x, it = blockIdx.y, zs = blockIdx.z, t = threadIdx.x;
    const float* proj = ws + OFF_PROJ;
    const float* vpg  = ws + OFF_VPG;
    const float* att  = ws + OFF_ATT + (size_t)h*NSQ;
    int c = t & 63, isub = t >> 6;
    float acc[8] = {0,0,0,0,0,0,0,0};
    for (int jt = zs*2; jt < zs*2+2; jt++){
        __syncthreads();
        for (int ix = t; ix < 128*40; ix += 256){
            int jj = ix / 40, cc = ix % 40;
            int j = jt*128 + jj;
            wlds[jj][cc] = (cc < 16) ? proj[(size_t)j*1152 + 384 + h*16 + cc]
                                     : vpg[(size_t)j*288 + h*24 + (cc - 16)];
        }
        for (int ix = t; ix < 32*128; ix += 256){
            int rr = ix >> 7, jj = ix & 127;
            plds[rr][jj] = att[(size_t)(it*32 + rr)*NN + jt*128 + jj];
        }
        __syncthreads();
        if (c < 40){
            for (int jj = 0; jj < 128; jj += 4){
                float w0 = wlds[jj][c], w1 = wlds[jj+1][c], w2 = wlds[jj+2][c], w3 = wlds[jj+3][c];
                #pragma unroll
                for (int rr = 0; rr < 8; rr++){
                    floatx4 pv = *(floatx4*)&plds[isub*8+rr][jj];
                    acc[rr] += pv[0]*w0 + pv[1]*w1 + pv[2]*w2 + pv[3]*w3;
                }
            }
        }
    }
    if (c < 40){
        float* ocat = ws + OFF_OCAT;
        int col = (c < 16) ? (h*16 + c) : (576 + h*24 + (c - 16));
        for (int rr = 0; rr < 8; rr++){
            int i = it*32 + isub*8 + rr;
            atomicAdd(&ocat[(size_t)i*960 + col], acc[rr]);
        }
    }
}

// ---- K6: o_pair: grid (i, jt). pz bf16.
__global__ __launch_bounds__(384) void k_opair(const int* __restrict__ idx, float* __restrict__ ws){
    __shared__ float plds[12][132];
    __shared__ float pzlds[128][33];
    int i = blockIdx.x, jt = blockIdx.y, t = threadIdx.x;
    int ires = idx[i];
    const unsigned int* pzg = (const unsigned int*)((const unsigned short*)(ws + OFF_PZ) + (size_t)ires*NN*32);
    const float* att = ws + OFF_ATT;
    for (int ix = t; ix < 12*128; ix += 384){
        int hh = ix >> 7, jj = ix & 127;
        plds[hh][jj] = att[(size_t)hh*NSQ + (size_t)i*NN + jt*128 + jj];
    }
    for (int ix = t; ix < 128*16; ix += 384){
        int jj = ix >> 4, cp = ix & 15;
        int jres = idx[jt*128 + jj];
        unsigned int u2 = pzg[(size_t)jres*16 + cp];
        pzlds[jj][cp*2]   = __uint_as_float(u2 << 16);
        pzlds[jj][cp*2+1] = __uint_as_float(u2 & 0xffff0000u);
    }
    __syncthreads();
    int h = t >> 5, c = t & 31;
    float acc = 0.f;
    #pragma unroll 4
    for (int j = 0; j < 128; j++)
        acc += plds[h][j] * pzlds[j][c];
    float* oc = ws + OFF_OCAT + (size_t)i*960 + 192;
    atomicAdd(&oc[h*32 + c], acc);
}

// ---- K6b: o_pt local frame + norms
__global__ __launch_bounds__(96) void k_ptfin(const float* __restrict__ rot, const float* __restrict__ trans,
                                              float* __restrict__ ws){
    int i = blockIdx.x, p = threadIdx.x;
    float* base = ws + OFF_OCAT + (size_t)i*960;
    float* pt = base + 576 + p*3;
    float x = pt[0] - trans[i*3+0];
    float y = pt[1] - trans[i*3+1];
    float z = pt[2] - trans[i*3+2];
    const float* R = rot + (size_t)i*9;
    float lx = R[0]*x + R[3]*y + R[6]*z;
    float ly = R[1]*x + R[4]*y + R[7]*z;
    float lz = R[2]*x + R[5]*y + R[8]*z;
    pt[0] = lx; pt[1] = ly; pt[2] = lz;
    base[864 + p] = sqrtf(lx*lx + ly*ly + lz*lz + EPS_);
}

// ---- K7: final GEMM, k-split x4, 8x2 register tile, atomic into zeroed out
__global__ __launch_bounds__(256) void k_out(const float* __restrict__ Wout, const float* __restrict__ Woutb,
                                             const float* __restrict__ Woutp, float* __restrict__ ws,
                                             float* __restrict__ out){
    __shared__ float olds[32][244];
    int it = blockIdx.x, ct = blockIdx.y, kc = blockIdx.z, t = threadIdx.x;
    const float* ocat = ws + OFF_OCAT;
    for (int ix = t; ix < 32*240; ix += 256){
        int r = ix / 240, kk = ix % 240;
        olds[r][kk] = ocat[(size_t)(it*32 + r)*960 + kc*240 + kk];
    }
    __syncthreads();
    int cl = t & 63, ig = t >> 6;
    int c0 = ct*128 + cl, c1 = c0 + 64;
    float acc0[8], acc1[8];
    #pragma unroll
    for (int r=0;r<8;r++){ acc0[r]=0; acc1[r]=0; }
    for (int kk = 0; kk < 240; kk += 4){
        float w0[4], w1[4];
        #pragma unroll
        for (int u = 0; u < 4; u++){
            int k = kc*240 + kk + u;
            const float* wrow = (k < 192) ? (Wout  + (size_t)k*CS)
                              : (k < 576) ? (Woutb + (size_t)(k-192)*CS)
                                          : (Woutp + (size_t)(k-576)*CS);
            w0[u] = wrow[c0]; w1[u] = wrow[c1];
        }
        #pragma unroll
        for (int r = 0; r < 8; r++){
            floatx4 ov = *(const floatx4*)&olds[ig*8 + r][kk];
            acc0[r] += ov[0]*w0[0] + ov[1]*w0[1] + ov[2]*w0[2] + ov[3]*w0[3];
            acc1[r] += ov[0]*w1[0] + ov[1]*w1[1] + ov[2]*w1[2] + ov[3]*w1[3];
        }
    }
    for (int r = 0; r < 8; r++){
        int i = it*32 + ig*8 + r;
        atomicAdd(&out[(size_t)i*CS + c0], acc0[r]);
        atomicAdd(&out[(size_t)i*CS + c1], acc1[r]);
    }
}

extern "C" void kernel_launch(void* const* d_in, const int* in_sizes, int n_in,
                              void* d_out, int out_size, void* d_ws, size_t ws_size,
                              hipStream_t stream){
    const float* s     = (const float*)d_in[0];
    const float* z     = (const float*)d_in[1];
    const float* rot   = (const float*)d_in[2];
    const float* trans = (const float*)d_in[3];
    const float* smask = (const float*)d_in[4];
    const float* gs    = (const float*)d_in[5];
    const float* bs    = (const float*)d_in[6];
    const float* gz    = (const float*)d_in[7];
    const float* bz    = (const float*)d_in[8];
    const float* Wq    = (const float*)d_in[9];
    const float* Wk    = (const float*)d_in[10];
    const float* Wv    = (const float*)d_in[11];
    const float* Wqp   = (const float*)d_in[12];
    const float* Wkp   = (const float*)d_in[13];
    const float* Wvp   = (const float*)d_in[14];
    const float* Wb    = (const float*)d_in[15];
    const float* Wdz   = (const float*)d_in[16];
    const float* hwin  = (const float*)d_in[17];
    const float* Wout  = (const float*)d_in[18];
    const float* Woutb = (const float*)d_in[19];
    const float* Woutp = (const float*)d_in[20];
    const int*   idx   = (const int*)d_in[21];
    float* ws  = (float*)d_ws;
    float* out = (float*)d_out;

    k_setup  <<<4057, 256, 0, stream>>>(Wb, Wdz, hwin, ws, out);
    k_proj   <<<dim3(48, 9), 256, 0, stream>>>(s, gs, bs, Wq, Wk, Wv, Wqp, Wkp, Wvp, ws);
    k_pts    <<<768, 192, 0, stream>>>(rot, trans, ws);
    k_feat   <<<768, 256, 0, stream>>>(ws);
    k_z      <<<9216, 256, 0, stream>>>(z, gz, bz, ws);
    k_lg     <<<dim3(12, 12, 12), 256, 0, stream>>>(smask, idx, ws);
    k_softmax<<<2304, 256, 0, stream>>>(ws);
    k_ov     <<<dim3(12, 24, 3), 256, 0, stream>>>(ws);
    k_opair  <<<dim3(768, 6), 384, 0, stream>>>(idx, ws);
    k_ptfin  <<<768, 96, 0, stream>>>(rot, trans, ws);
    k_out    <<<dim3(24, 3, 4), 256, 0, stream>>>(Wout, Woutb, Woutp, ws, out);
}

// Round 6
// 669.652 us; speedup vs baseline: 1.5214x; 1.0356x over previous
//
#include <hip/hip_runtime.h>
#include <hip/hip_bf16.h>

#define NN 768
#define NSQ (768*768)
#define CS 384
#define CZ 128
#define HH 12
#define INF_ 1e5f
#define EPS_ 1e-8f
#define LN_EPS_ 1e-5f

typedef __attribute__((ext_vector_type(8))) short short8;
typedef __attribute__((ext_vector_type(4))) short short4_t;
typedef __attribute__((ext_vector_type(4))) float floatx4;

// ---- workspace layout (float element offsets) ----
constexpr size_t OFF_SLN  = 0;                           // 768*384 (unused, layout stability)
constexpr size_t OFF_PROJ = OFF_SLN + (size_t)768*384;   // 768*1152 : [q|k|v|qp|kp|vp]
constexpr size_t OFF_QPG  = OFF_PROJ + (size_t)768*1152; // 768*144
constexpr size_t OFF_KPG  = OFF_QPG + (size_t)768*144;   // 768*144
constexpr size_t OFF_VPG  = OFF_KPG + (size_t)768*144;   // 768*288
constexpr size_t OFF_WTBF = OFF_VPG + (size_t)768*288;   // 48*128 bf16
constexpr size_t OFF_HW   = OFF_WTBF + 4096;             // 16
constexpr size_t OFF_BIAS = OFF_HW + 16;                 // NSQ*12 bf16  (= NSQ*6 floats)
constexpr size_t OFF_ATT  = OFF_BIAS + (size_t)NSQ*6;    // 12*NSQ floats (logits -> f32 probs in place)
constexpr size_t OFF_PZ   = OFF_ATT + (size_t)12*NSQ;    // pzT[32][NSQ] bf16 (= NSQ*16 floats)
constexpr size_t OFF_OCAT = OFF_PZ + (size_t)NSQ*16;     // 768*960
constexpr size_t OFF_ABF  = OFF_OCAT + (size_t)768*960;  // 12*768*64 bf16 = 294912 floats
constexpr size_t OFF_BBF  = OFF_ABF + 294912;            // 12*768*64 bf16
constexpr size_t OFF_CJ   = OFF_BBF + 294912;            // 12*768 floats
constexpr size_t OFF_ATTB = OFF_CJ + 9216;               // probs bf16 [12][768][768] (= NSQ*6 floats)

__device__ __forceinline__ unsigned short f2bf(float f){
    unsigned int u = __float_as_uint(f);
    u = (u + 0x7fffu + ((u >> 16) & 1u)) >> 16;
    return (unsigned short)u;
}
__device__ __forceinline__ float bf2f(unsigned short u){
    return __uint_as_float((unsigned int)u << 16);
}

// ---- K0: zero ocat + zero out + bf16 W^T + softplus(head_weights)
__global__ __launch_bounds__(256) void k_setup(const float* __restrict__ Wb, const float* __restrict__ Wdz,
                                               const float* __restrict__ hwin, float* __restrict__ ws,
                                               float* __restrict__ out){
    int b = blockIdx.x, t = threadIdx.x;
    if (b < 2880){ ws[OFF_OCAT + (size_t)b*256 + t] = 0.f; return; }
    b -= 2880;
    if (b < 1152){ out[(size_t)b*256 + t] = 0.f; return; }
    b -= 1152;
    if (b < 24){
        unsigned short* wt = (unsigned short*)(ws + OFF_WTBF);
        int o = b*2 + (t>>7), k = t & 127;
        float v = 0.f;
        if (o < HH) v = Wb[k*HH + o];
        else if (o < 44) v = Wdz[k*32 + (o - HH)];
        wt[o*128 + k] = f2bf(v);
        return;
    }
    b -= 24;
    if (b == 0 && t < HH){
        ws[OFF_HW + t] = log1pf(expf(hwin[t])) * sqrtf(1.0f/54.0f);
    }
}

// ---- K2: LN(s) fused + projections, (768x384) @ W (384x1152)
__global__ __launch_bounds__(256) void k_proj(const float* __restrict__ s, const float* __restrict__ gs,
                                              const float* __restrict__ bs,
                                              const float* __restrict__ Wq, const float* __restrict__ Wk,
                                              const float* __restrict__ Wv, const float* __restrict__ Wqp,
                                              const float* __restrict__ Wkp, const float* __restrict__ Wvp,
                                              float* __restrict__ ws){
    __shared__ float slds[16][CS];
    __shared__ float stats[16][2];
    int rt = blockIdx.x, ct = blockIdx.y, t = threadIdx.x;
    for (int ix = t; ix < 16*CS; ix += 256){
        int r = ix / CS, c = ix % CS;
        slds[r][c] = s[(size_t)(rt*16 + r)*CS + c];
    }
    __syncthreads();
    int w = t >> 6, lane = t & 63;
    for (int r = w; r < 16; r += 4){
        float sum = 0.f, sq = 0.f;
        #pragma unroll
        for (int c0 = 0; c0 < CS; c0 += 64){
            float x = slds[r][c0 + lane];
            sum += x; sq += x*x;
        }
        #pragma unroll
        for (int off = 32; off; off >>= 1){
            sum += __shfl_xor(sum, off, 64);
            sq  += __shfl_xor(sq , off, 64);
        }
        if (lane == 0){
            float mu = sum * (1.0f/CS);
            float var = sq * (1.0f/CS) - mu*mu;
            stats[r][0] = mu;
            stats[r][1] = rsqrtf(var + LN_EPS_);
        }
    }
    __syncthreads();
    for (int ix = t; ix < 16*CS; ix += 256){
        int r = ix / CS, c = ix % CS;
        slds[r][c] = (slds[r][c] - stats[r][0]) * stats[r][1] * gs[c] + bs[c];
    }
    __syncthreads();
    int col = ct*128 + (t & 127);
    int rg = t >> 7;
    const float* wp; int stride;
    if      (col < 192){ wp = Wq  + col;       stride = 192; }
    else if (col < 384){ wp = Wk  + (col-192); stride = 192; }
    else if (col < 576){ wp = Wv  + (col-384); stride = 192; }
    else if (col < 720){ wp = Wqp + (col-576); stride = 144; }
    else if (col < 864){ wp = Wkp + (col-720); stride = 144; }
    else               { wp = Wvp + (col-864); stride = 288; }
    float acc[8] = {0,0,0,0,0,0,0,0};
    for (int k = 0; k < CS; k += 4){
        float w0 = wp[(size_t)k*stride];
        float w1 = wp[(size_t)(k+1)*stride];
        float w2 = wp[(size_t)(k+2)*stride];
        float w3 = wp[(size_t)(k+3)*stride];
        #pragma unroll
        for (int r = 0; r < 8; r++){
            floatx4 sv = *(const floatx4*)&slds[rg*8+r][k];
            acc[r] += sv[0]*w0 + sv[1]*w1 + sv[2]*w2 + sv[3]*w3;
        }
    }
    float* proj = ws + OFF_PROJ;
    for (int r = 0; r < 8; r++) proj[(size_t)(rt*16 + rg*8 + r)*1152 + col] = acc[r];
}

// ---- K2b: points to global frame + logits feature build (merged)
__global__ __launch_bounds__(256) void k_ptsfeat(const float* __restrict__ rot, const float* __restrict__ trans,
                                                 float* __restrict__ ws){
    __shared__ float qp[144];
    __shared__ float kp[144];
    int i = blockIdx.x, t = threadIdx.x;
    const float* proj = ws + OFF_PROJ + (size_t)i*1152;
    if (t < 192){
        int p = t;
        const float* src; float* dst; float* lbuf = nullptr;
        if (p < 48)      { src = proj + 576 + p*3;      dst = ws + OFF_QPG + (size_t)i*144 + p*3; lbuf = qp + p*3; }
        else if (p < 96) { src = proj + 720 + (p-48)*3; dst = ws + OFF_KPG + (size_t)i*144 + (p-48)*3; lbuf = kp + (p-48)*3; }
        else             { src = proj + 864 + (p-96)*3; dst = ws + OFF_VPG + (size_t)i*288 + (p-96)*3; }
        float x = src[0], y = src[1], z = src[2];
        const float* R = rot + (size_t)i*9;
        const float* T = trans + (size_t)i*3;
        float gx = R[0]*x + R[1]*y + R[2]*z + T[0];
        float gy = R[3]*x + R[4]*y + R[5]*z + T[1];
        float gz = R[6]*x + R[7]*y + R[8]*z + T[2];
        dst[0] = gx; dst[1] = gy; dst[2] = gz;
        if (lbuf){ lbuf[0] = gx; lbuf[1] = gy; lbuf[2] = gz; }
    }
    __syncthreads();
    unsigned short* Abf = (unsigned short*)(ws + OFF_ABF);
    unsigned short* Bbf = (unsigned short*)(ws + OFF_BBF);
    const float S1 = 0.14433756729740643f;
    for (int ix = t; ix < 12*64; ix += 256){
        int h = ix >> 6, c = ix & 63;
        float hwv = ws[OFF_HW + h];
        unsigned short ab = 0, bb = 0;
        if (c < 16){
            ab = f2bf(proj[h*16 + c]);
            bb = f2bf(S1 * proj[192 + h*16 + c]);
        } else if (c < 28){
            int d = c - 16;
            ab = f2bf(qp[h*12 + d]);
            bb = f2bf(hwv * kp[h*12 + d]);
        } else if (c < 40){
            int d = c - 28;
            float q = qp[h*12 + d];
            unsigned short hi = f2bf(q);
            ab = f2bf(q - bf2f(hi));
            bb = f2bf(hwv * kp[h*12 + d]);
        } else if (c < 52){
            int d = c - 40;
            ab = f2bf(qp[h*12 + d]);
            float x = hwv * kp[h*12 + d];
            unsigned short xh = f2bf(x);
            bb = f2bf(x - bf2f(xh));
        }
        Abf[((size_t)h*768 + i)*64 + c] = ab;
        Bbf[((size_t)h*768 + i)*64 + c] = bb;
    }
    if (t < 12){
        float hwv = ws[OFF_HW + t];
        float s2 = 0.f;
        #pragma unroll
        for (int d = 0; d < 12; d++){ float k = kp[t*12 + d]; s2 += k*k; }
        ws[OFF_CJ + (size_t)t*768 + i] = -0.5f * hwv * s2;
    }
}

// ---- K3: LN(z) + [Wb|Wdz] via bf16 MFMA; bias bf16 [h][pair], pz bf16 TRANSPOSED [c][pair]
__global__ __launch_bounds__(256) void k_z(const float* __restrict__ z, const float* __restrict__ gz,
                                           const float* __restrict__ bz, float* __restrict__ ws){
    __shared__ unsigned short zlds[64][136];
    int t = threadIdx.x;
    int pb = blockIdx.x * 64;
    int lane32 = t & 31;
    int col = lane32 * 4;
    floatx4 g4 = *(const floatx4*)(gz + col);
    floatx4 b4 = *(const floatx4*)(bz + col);
    const float* zbase = z + (size_t)pb * 128;
    #pragma unroll
    for (int g = 0; g < 8; g++){
        int row = g*8 + (t >> 5);
        floatx4 v = *(const floatx4*)(zbase + (size_t)g*1024 + (size_t)t*4);
        float sum = v[0]+v[1]+v[2]+v[3];
        float sq  = v[0]*v[0]+v[1]*v[1]+v[2]*v[2]+v[3]*v[3];
        #pragma unroll
        for (int off = 1; off <= 16; off <<= 1){
            sum += __shfl_xor(sum, off, 64);
            sq  += __shfl_xor(sq , off, 64);
        }
        float mu = sum * (1.0f/128.0f);
        float rstd = rsqrtf(sq*(1.0f/128.0f) - mu*mu + LN_EPS_);
        short4_t sv;
        sv[0] = (short)f2bf((v[0]-mu)*rstd*g4[0] + b4[0]);
        sv[1] = (short)f2bf((v[1]-mu)*rstd*g4[1] + b4[1]);
        sv[2] = (short)f2bf((v[2]-mu)*rstd*g4[2] + b4[2]);
        sv[3] = (short)f2bf((v[3]-mu)*rstd*g4[3] + b4[3]);
        *(short4_t*)&zlds[row][col] = sv;
    }
    __syncthreads();
    const unsigned short* wt = (const unsigned short*)(ws + OFF_WTBF);
    int lane = t & 63, wv = t >> 6;
    int m = lane & 15, quad = lane >> 4;
    short8 bfrag[3][4];
    #pragma unroll
    for (int ot = 0; ot < 3; ot++)
        #pragma unroll
        for (int ks = 0; ks < 4; ks++){
            int o = ot*16 + m;
            bfrag[ot][ks] = *(const short8*)(wt + o*128 + ks*32 + quad*8);
        }
    floatx4 acc[3] = {{0.f,0.f,0.f,0.f},{0.f,0.f,0.f,0.f},{0.f,0.f,0.f,0.f}};
    int rbase = wv*16;
    #pragma unroll
    for (int ks = 0; ks < 4; ks++){
        short8 a = *(const short8*)&zlds[rbase + m][ks*32 + quad*8];
        acc[0] = __builtin_amdgcn_mfma_f32_16x16x32_bf16(a, bfrag[0][ks], acc[0], 0, 0, 0);
        acc[1] = __builtin_amdgcn_mfma_f32_16x16x32_bf16(a, bfrag[1][ks], acc[1], 0, 0, 0);
        acc[2] = __builtin_amdgcn_mfma_f32_16x16x32_bf16(a, bfrag[2][ks], acc[2], 0, 0, 0);
    }
    __syncthreads();
    unsigned short* stb = &zlds[0][0];          // [64][12] rp-major
    unsigned short* stp = &zlds[0][0] + 64*12;  // [64][34] rp-major (padded)
    #pragma unroll
    for (int ot = 0; ot < 3; ot++){
        int o = ot*16 + m;
        #pragma unroll
        for (int rg = 0; rg < 4; rg++){
            int rp = rbase + quad*4 + rg;
            float val = acc[ot][rg];
            if (o < HH)      stb[rp*12 + o] = f2bf(val);
            else if (o < 44) stp[rp*34 + (o - HH)] = f2bf(val);
        }
    }
    __syncthreads();
    unsigned short* bias16 = (unsigned short*)(ws + OFF_BIAS);
    unsigned int*   pzT32  = (unsigned int*)((unsigned short*)(ws + OFF_PZ));
    for (int ix = t; ix < 12*32; ix += 256){
        int o = ix >> 5, u = ix & 31;
        unsigned int val = (unsigned int)stb[(u*2)*12 + o] | ((unsigned int)stb[(u*2+1)*12 + o] << 16);
        *(unsigned int*)(bias16 + (size_t)o*NSQ + pb + u*2) = val;
    }
    for (int ix = t; ix < 32*32; ix += 256){
        int c = ix >> 5, u = ix & 31;
        unsigned int val = (unsigned int)stp[(u*2)*34 + c] | ((unsigned int)stp[(u*2+1)*34 + c] << 16);
        pzT32[(size_t)c*(NSQ/2) + (pb >> 1) + u] = val;
    }
}

// ---- K4: logits via MFMA. grid (12 it, 12 jt, 12 h), 64x64 tile per block.
__global__ __launch_bounds__(256) void k_lg(const float* __restrict__ smask, const int* __restrict__ idx,
                                            float* __restrict__ ws){
    __shared__ unsigned short Al[64][64];
    __shared__ unsigned short Bl[64][64];
    __shared__ int   idJ[64];
    __shared__ float sIv[64];
    __shared__ float sjv[64];
    __shared__ float cjv[64];
    int it = blockIdx.x, jt = blockIdx.y, h = blockIdx.z, t = threadIdx.x;
    const unsigned int* Ag = (const unsigned int*)((const unsigned short*)(ws + OFF_ABF) + ((size_t)h*768 + it*64)*64);
    const unsigned int* Bg = (const unsigned int*)((const unsigned short*)(ws + OFF_BBF) + ((size_t)h*768 + jt*64)*64);
    for (int ix = t; ix < 64*32; ix += 256){
        int r = ix >> 5, u = ix & 31;
        int gs = ((u >> 2) ^ (r & 7));
        int us = (gs << 2) | (u & 3);
        ((unsigned int*)&Al[r][0])[us] = Ag[ix];
        ((unsigned int*)&Bl[r][0])[us] = Bg[ix];
    }
    if (t < 64){
        int i = it*64 + t, j = jt*64 + t;
        int ii = idx[i], jj = idx[j];
        sIv[t] = smask[ii];
        idJ[t] = jj;
        sjv[t] = INF_ * 0.57735026918962576f * (smask[jj] - 1.0f);
        cjv[t] = ws[OFF_CJ + (size_t)h*768 + j];
    }
    __syncthreads();
    int lane = t & 63, w = t >> 6;
    int m = lane & 15, quad = lane >> 4;
    short8 af0, af1;
    {
        int r = w*16 + m;
        int g0 = (quad) ^ (r & 7);
        int g1 = (quad + 4) ^ (r & 7);
        af0 = *(const short8*)&Al[r][g0*8];
        af1 = *(const short8*)&Al[r][g1*8];
    }
    floatx4 acc[4] = {{0.f,0.f,0.f,0.f},{0.f,0.f,0.f,0.f},{0.f,0.f,0.f,0.f},{0.f,0.f,0.f,0.f}};
    #pragma unroll
    for (int nt = 0; nt < 4; nt++){
        int r = nt*16 + m;
        int g0 = (quad) ^ (r & 7);
        int g1 = (quad + 4) ^ (r & 7);
        short8 bf0 = *(const short8*)&Bl[r][g0*8];
        short8 bf1 = *(const short8*)&Bl[r][g1*8];
        acc[nt] = __builtin_amdgcn_mfma_f32_16x16x32_bf16(af0, bf0, acc[nt], 0, 0, 0);
        acc[nt] = __builtin_amdgcn_mfma_f32_16x16x32_bf16(af1, bf1, acc[nt], 0, 0, 0);
    }
    const unsigned short* bias16 = (const unsigned short*)(ws + OFF_BIAS) + (size_t)h*NSQ;
    float* att = ws + OFF_ATT + (size_t)h*NSQ;
    const float S2 = 0.57735026918962576f;
    #pragma unroll
    for (int rg = 0; rg < 4; rg++){
        int il = w*16 + quad*4 + rg;
        int i  = it*64 + il;
        int ires = idx[i];
        float si = sIv[il];
        const unsigned short* brow = bias16 + (size_t)ires*NN;
        float* arow = att + (size_t)i*NN + jt*64;
        #pragma unroll
        for (int nt = 0; nt < 4; nt++){
            int jl = nt*16 + m;
            float bv = bf2f(brow[idJ[jl]]);
            arow[jl] = acc[nt][rg] + S2*bv + si*sjv[jl] + cjv[jl];
        }
    }
}

// ---- K4c: softmax, one wave per row; writes f32 probs in place + bf16 copy
__global__ __launch_bounds__(256) void k_softmax(float* __restrict__ ws){
    int t = threadIdx.x;
    int w = t >> 6, lane = t & 63;
    size_t rowi = (size_t)blockIdx.x*4 + w;
    float* row = ws + OFF_ATT + rowi*NN;
    floatx4 v0 = *(const floatx4*)(row + lane*4);
    floatx4 v1 = *(const floatx4*)(row + 256 + lane*4);
    floatx4 v2 = *(const floatx4*)(row + 512 + lane*4);
    float mx = fmaxf(fmaxf(fmaxf(v0[0],v0[1]), fmaxf(v0[2],v0[3])),
               fmaxf(fmaxf(fmaxf(v1[0],v1[1]), fmaxf(v1[2],v1[3])),
                     fmaxf(fmaxf(v2[0],v2[1]), fmaxf(v2[2],v2[3]))));
    #pragma unroll
    for (int off = 32; off; off >>= 1) mx = fmaxf(mx, __shfl_xor(mx, off, 64));
    floatx4 e0, e1, e2;
    #pragma unroll
    for (int u = 0; u < 4; u++){ e0[u] = expf(v0[u]-mx); e1[u] = expf(v1[u]-mx); e2[u] = expf(v2[u]-mx); }
    float s = e0[0]+e0[1]+e0[2]+e0[3] + e1[0]+e1[1]+e1[2]+e1[3] + e2[0]+e2[1]+e2[2]+e2[3];
    #pragma unroll
    for (int off = 32; off; off >>= 1) s += __shfl_xor(s, off, 64);
    float inv = 1.0f / s;
    #pragma unroll
    for (int u = 0; u < 4; u++){ e0[u] *= inv; e1[u] *= inv; e2[u] *= inv; }
    *(floatx4*)(row + lane*4) = e0;
    *(floatx4*)(row + 256 + lane*4) = e1;
    *(floatx4*)(row + 512 + lane*4) = e2;
    unsigned short* brow = (unsigned short*)(ws + OFF_ATTB) + rowi*NN;
    short4_t o0, o1, o2;
    #pragma unroll
    for (int u = 0; u < 4; u++){
        o0[u] = (short)f2bf(e0[u]);
        o1[u] = (short)f2bf(e1[u]);
        o2[u] = (short)f2bf(e2[u]);
    }
    *(short4_t*)(brow + lane*4) = o0;
    *(short4_t*)(brow + 256 + lane*4) = o1;
    *(short4_t*)(brow + 512 + lane*4) = o2;
}

// ---- K5: o and o_pt(global), j-split x3, atomic accumulate (f32 — o_pt needs precision)
__global__ __launch_bounds__(256) void k_ov(float* __restrict__ ws){
    __shared__ float wlds[128][41];
    __shared__ float plds[32][128];
    int h = blockIdx.x, it = blockIdx.y, zs = blockIdx.z, t = threadIdx.x;
    const float* proj = ws + OFF_PROJ;
    const float* vpg  = ws + OFF_VPG;
    const float* att  = ws + OFF_ATT + (size_t)h*NSQ;
    int c = t & 63, isub = t >> 6;
    float acc[8] = {0,0,0,0,0,0,0,0};
    for (int jt = zs*2; jt < zs*2+2; jt++){
        __syncthreads();
        for (int ix = t; ix < 128*40; ix += 256){
            int jj = ix / 40, cc = ix % 40;
            int j = jt*128 + jj;
            wlds[jj][cc] = (cc < 16) ? proj[(size_t)j*1152 + 384 + h*16 + cc]
                                     : vpg[(size_t)j*288 + h*24 + (cc - 16)];
        }
        for (int ix = t; ix < 32*128; ix += 256){
            int rr = ix >> 7, jj = ix & 127;
            plds[rr][jj] = att[(size_t)(it*32 + rr)*NN + jt*128 + jj];
        }
        __syncthreads();
        if (c < 40){
            for (int jj = 0; jj < 128; jj += 4){
                float w0 = wlds[jj][c], w1 = wlds[jj+1][c], w2 = wlds[jj+2][c], w3 = wlds[jj+3][c];
                #pragma unroll
                for (int rr = 0; rr < 8; rr++){
                    floatx4 pv = *(floatx4*)&plds[isub*8+rr][jj];
                    acc[rr] += pv[0]*w0 + pv[1]*w1 + pv[2]*w2 + pv[3]*w3;
                }
            }
        }
    }
    if (c < 40){
        float* ocat = ws + OFF_OCAT;
        int col = (c < 16) ? (h*16 + c) : (576 + h*24 + (c - 16));
        for (int rr = 0; rr < 8; rr++){
            int i = it*32 + isub*8 + rr;
            atomicAdd(&ocat[(size_t)i*960 + col], acc[rr]);
        }
    }
}

// ---- K6: o_pair via MFMA: probs bf16 (12x128, pad 16) @ pzT^T(128x32), grid (i, jt)
__global__ __launch_bounds__(128) void k_opair(const int* __restrict__ idx, float* __restrict__ ws){
    __shared__ unsigned short Ald[16][136];
    __shared__ unsigned short Bld[32][136];
    __shared__ int jres[128];
    int i = blockIdx.x, jt = blockIdx.y, t = threadIdx.x;
    int ires = idx[i];
    const unsigned short* attb = (const unsigned short*)(ws + OFF_ATTB);
    const unsigned short* pzT  = (const unsigned short*)(ws + OFF_PZ);
    int jb = jt*128;
    jres[t] = idx[jb + t];
    __syncthreads();
    for (int ix = t; ix < 16*16; ix += 128){
        int r = ix >> 4, u = ix & 15;
        uint4 v = {0,0,0,0};
        if (r < 12) v = *(const uint4*)(attb + (size_t)r*NSQ + (size_t)i*NN + jb + u*8);
        *(uint4*)&Ald[r][u*8] = v;
    }
    size_t rowoff = (size_t)ires*NN;
    for (int ix = t; ix < 32*128; ix += 128){
        int c = ix >> 7, jj = ix & 127;
        Bld[c][jj] = pzT[(size_t)c*NSQ + rowoff + jres[jj]];
    }
    __syncthreads();
    int lane = t & 63, wv = t >> 6;
    int m = lane & 15, quad = lane >> 4;
    floatx4 acc = {0.f,0.f,0.f,0.f};
    #pragma unroll
    for (int ks = 0; ks < 4; ks++){
        short8 a = *(const short8*)&Ald[m][ks*32 + quad*8];
        short8 b = *(const short8*)&Bld[wv*16 + m][ks*32 + quad*8];
        acc = __builtin_amdgcn_mfma_f32_16x16x32_bf16(a, b, acc, 0, 0, 0);
    }
    float* oc = ws + OFF_OCAT + (size_t)i*960 + 192;
    #pragma unroll
    for (int rg = 0; rg < 4; rg++){
        int hh = quad*4 + rg;
        if (hh < 12) atomicAdd(&oc[hh*32 + wv*16 + m], acc[rg]);
    }
}

// ---- K6b: o_pt local frame + norms
__global__ __launch_bounds__(96) void k_ptfin(const float* __restrict__ rot, const float* __restrict__ trans,
                                              float* __restrict__ ws){
    int i = blockIdx.x, p = threadIdx.x;
    float* base = ws + OFF_OCAT + (size_t)i*960;
    float* pt = base + 576 + p*3;
    float x = pt[0] - trans[i*3+0];
    float y = pt[1] - trans[i*3+1];
    float z = pt[2] - trans[i*3+2];
    const float* R = rot + (size_t)i*9;
    float lx = R[0]*x + R[3]*y + R[6]*z;
    float ly = R[1]*x + R[4]*y + R[7]*z;
    float lz = R[2]*x + R[5]*y + R[8]*z;
    pt[0] = lx; pt[1] = ly; pt[2] = lz;
    base[864 + p] = sqrtf(lx*lx + ly*ly + lz*lz + EPS_);
}

// ---- K7: final GEMM, k-split x4, 8x2 register tile, atomic into zeroed out
__global__ __launch_bounds__(256) void k_out(const float* __restrict__ Wout, const float* __restrict__ Woutb,
                                             const float* __restrict__ Woutp, float* __restrict__ ws,
                                             float* __restrict__ out){
    __shared__ float olds[32][244];
    int it = blockIdx.x, ct = blockIdx.y, kc = blockIdx.z, t = threadIdx.x;
    const float* ocat = ws + OFF_OCAT;
    for (int ix = t; ix < 32*240; ix += 256){
        int r = ix / 240, kk = ix % 240;
        olds[r][kk] = ocat[(size_t)(it*32 + r)*960 + kc*240 + kk];
    }
    __syncthreads();
    int cl = t & 63, ig = t >> 6;
    int c0 = ct*128 + cl, c1 = c0 + 64;
    float acc0[8], acc1[8];
    #pragma unroll
    for (int r=0;r<8;r++){ acc0[r]=0; acc1[r]=0; }
    for (int kk = 0; kk < 240; kk += 4){
        float w0[4], w1[4];
        #pragma unroll
        for (int u = 0; u < 4; u++){
            int k = kc*240 + kk + u;
            const float* wrow = (k < 192) ? (Wout  + (size_t)k*CS)
                              : (k < 576) ? (Woutb + (size_t)(k-192)*CS)
                                          : (Woutp + (size_t)(k-576)*CS);
            w0[u] = wrow[c0]; w1[u] = wrow[c1];
        }
        #pragma unroll
        for (int r = 0; r < 8; r++){
            floatx4 ov = *(const floatx4*)&olds[ig*8 + r][kk];
            acc0[r] += ov[0]*w0[0] + ov[1]*w0[1] + ov[2]*w0[2] + ov[3]*w0[3];
            acc1[r] += ov[0]*w1[0] + ov[1]*w1[1] + ov[2]*w1[2] + ov[3]*w1[3];
        }
    }
    for (int r = 0; r < 8; r++){
        int i = it*32 + ig*8 + r;
        atomicAdd(&out[(size_t)i*CS + c0], acc0[r]);
        atomicAdd(&out[(size_t)i*CS + c1], acc1[r]);
    }
}

extern "C" void kernel_launch(void* const* d_in, const int* in_sizes, int n_in,
                              void* d_out, int out_size, void* d_ws, size_t ws_size,
                              hipStream_t stream){
    const float* s     = (const float*)d_in[0];
    const float* z     = (const float*)d_in[1];
    const float* rot   = (const float*)d_in[2];
    const float* trans = (const float*)d_in[3];
    const float* smask = (const float*)d_in[4];
    const float* gs    = (const float*)d_in[5];
    const float* bs    = (const float*)d_in[6];
    const float* gz    = (const float*)d_in[7];
    const float* bz    = (const float*)d_in[8];
    const float* Wq    = (const float*)d_in[9];
    const float* Wk    = (const float*)d_in[10];
    const float* Wv    = (const float*)d_in[11];
    const float* Wqp   = (const float*)d_in[12];
    const float* Wkp   = (const float*)d_in[13];
    const float* Wvp   = (const float*)d_in[14];
    const float* Wb    = (const float*)d_in[15];
    const float* Wdz   = (const float*)d_in[16];
    const float* hwin  = (const float*)d_in[17];
    const float* Wout  = (const float*)d_in[18];
    const float* Woutb = (const float*)d_in[19];
    const float* Woutp = (const float*)d_in[20];
    const int*   idx   = (const int*)d_in[21];
    float* ws  = (float*)d_ws;
    float* out = (float*)d_out;

    k_setup  <<<4057, 256, 0, stream>>>(Wb, Wdz, hwin, ws, out);
    k_proj   <<<dim3(48, 9), 256, 0, stream>>>(s, gs, bs, Wq, Wk, Wv, Wqp, Wkp, Wvp, ws);
    k_ptsfeat<<<768, 256, 0, stream>>>(rot, trans, ws);
    k_z      <<<9216, 256, 0, stream>>>(z, gz, bz, ws);
    k_lg     <<<dim3(12, 12, 12), 256, 0, stream>>>(smask, idx, ws);
    k_softmax<<<2304, 256, 0, stream>>>(ws);
    k_ov     <<<dim3(12, 24, 3), 256, 0, stream>>>(ws);
    k_opair  <<<dim3(768, 6), 128, 0, stream>>>(idx, ws);
    k_ptfin  <<<768, 96, 0, stream>>>(rot, trans, ws);
    k_out    <<<dim3(24, 3, 4), 256, 0, stream>>>(Wout, Woutb, Woutp, ws, out);
}